// Round 1
// baseline (37155.356 us; speedup 1.0000x reference)
//
#include <hip/hip_runtime.h>
#include <hip/hip_cooperative_groups.h>

namespace cg = cooperative_groups;

typedef __bf16 bf16x8 __attribute__((ext_vector_type(8)));
typedef float f32x4 __attribute__((ext_vector_type(4)));

#define HID 512
#define BATCH 1024
#define SEQL 512
#define NWG 256
#define NTHR 256

// ---- workspace layout (byte offsets) ----
#define OFF_ENH 0u          // enc_whh hi : 1536*512*2 = 1572864
#define OFF_ENL 1572864u    // enc_whh lo
#define OFF_DEH 3145728u    // dec_whh hi
#define OFF_DEL 4718592u    // dec_whh lo
#define OFF_W1H 6291456u    // w1 hi : 512*512*2 = 524288
#define OFF_W1L 6815744u    // w1 lo
#define OFF_HF0 7340032u    // h f32 ping : 1024*512*4 = 2097152
#define OFF_HF1 9437184u    // h f32 pong
#define OFF_HH0 11534336u   // h hi ping : 1 MB
#define OFF_HH1 12582912u
#define OFF_HL0 13631488u   // h lo ping
#define OFF_HL1 14680064u
#define OFF_FC1 15728640u   // fc1 f32 : 2 MB
#define WS_NEED 17825792u

__device__ __forceinline__ f32x4 mfma16(bf16x8 a, bf16x8 b, f32x4 c) {
  return __builtin_amdgcn_mfma_f32_16x16x32_bf16(a, b, c, 0, 0, 0);
}
__device__ __forceinline__ float sig_(float x) { return 1.0f / (1.0f + __expf(-x)); }
__device__ __forceinline__ float tanh_(float x) { return 1.0f - 2.0f / (__expf(2.0f * x) + 1.0f); }

__global__ void split_w(const float* __restrict__ a, __bf16* __restrict__ hi,
                        __bf16* __restrict__ lo, int n) {
  int i = blockIdx.x * blockDim.x + threadIdx.x;
  if (i < n) {
    float v = a[i];
    __bf16 h = (__bf16)v;
    hi[i] = h;
    lo[i] = (__bf16)(v - (float)h);
  }
}

// gh = h @ W^T over K=512, 3 gate blocks, bf16 hi/lo 3-pass split.
__device__ __forceinline__ void gh_gemm(const __bf16* __restrict__ Ah, const __bf16* __restrict__ Al,
                                        const __bf16* __restrict__ Bh, const __bf16* __restrict__ Bl,
                                        int aoff0, int aoff1, const int (&boffg)[3],
                                        f32x4 (&acc)[2][3]) {
#pragma unroll 4
  for (int kc = 0; kc < 16; ++kc) {
    const int ko = kc * 32;
    bf16x8 a0h = *(const bf16x8*)(Ah + aoff0 + ko);
    bf16x8 a0l = *(const bf16x8*)(Al + aoff0 + ko);
    bf16x8 a1h = *(const bf16x8*)(Ah + aoff1 + ko);
    bf16x8 a1l = *(const bf16x8*)(Al + aoff1 + ko);
#pragma unroll
    for (int g = 0; g < 3; ++g) {
      bf16x8 bh = *(const bf16x8*)(Bh + boffg[g] + ko);
      bf16x8 bl = *(const bf16x8*)(Bl + boffg[g] + ko);
      acc[0][g] = mfma16(a0h, bh, acc[0][g]);
      acc[0][g] = mfma16(a0l, bh, acc[0][g]);
      acc[0][g] = mfma16(a0h, bl, acc[0][g]);
      acc[1][g] = mfma16(a1h, bh, acc[1][g]);
      acc[1][g] = mfma16(a1l, bh, acc[1][g]);
      acc[1][g] = mfma16(a1h, bl, acc[1][g]);
    }
  }
}

__global__ void __launch_bounds__(NTHR, 1) seq2seq_main(
    const float* __restrict__ src,
    const float* __restrict__ enc_wih, const float* __restrict__ enc_bih,
    const float* __restrict__ enc_bhh,
    const float* __restrict__ dec_wih, const float* __restrict__ dec_bih,
    const float* __restrict__ dec_bhh,
    const float* __restrict__ b1, const float* __restrict__ w2, const float* __restrict__ b2,
    const int* __restrict__ hor, float* __restrict__ out, char* __restrict__ ws) {
  const __bf16* ench_hi = (const __bf16*)(ws + OFF_ENH);
  const __bf16* ench_lo = (const __bf16*)(ws + OFF_ENL);
  const __bf16* dech_hi = (const __bf16*)(ws + OFF_DEH);
  const __bf16* dech_lo = (const __bf16*)(ws + OFF_DEL);
  const __bf16* w1h = (const __bf16*)(ws + OFF_W1H);
  const __bf16* w1l = (const __bf16*)(ws + OFF_W1L);
  float* hfA = (float*)(ws + OFF_HF0);
  float* hfB = (float*)(ws + OFF_HF1);
  __bf16* hhA = (__bf16*)(ws + OFF_HH0);
  __bf16* hhB = (__bf16*)(ws + OFF_HH1);
  __bf16* hlA = (__bf16*)(ws + OFF_HL0);
  __bf16* hlB = (__bf16*)(ws + OFF_HL1);
  float* fc1 = (float*)(ws + OFF_FC1);

  cg::grid_group grid = cg::this_grid();

  // XCD-aware tile mapping: tiles sharing W-columns land on the same XCD's L2.
  const int w = blockIdx.x;
  const int xcd = w & 7;
  const int i2 = w >> 3;
  const int rt = i2 & 15;                 // batch-row tile (64 rows)
  const int ct = (xcd << 1) + (i2 >> 4);  // hidden-col tile (32 cols)
  const int tid = threadIdx.x;
  const int wv = tid >> 6;
  const int lane = tid & 63;
  const int wr = wv & 1;   // row half (32 rows)
  const int wc = wv >> 1;  // col half (16 cols)

  const int rowbase = rt * 64 + wr * 32;
  const int c = ct * 32 + wc * 16 + (lane & 15);  // this lane's hidden column
  const int kb = (lane >> 4) << 3;                // k-offset within fragment
  const int aoff0 = (rowbase + (lane & 15)) * HID + kb;
  const int aoff1 = aoff0 + (HID << 4);

  int boffg[3];
#pragma unroll
  for (int g = 0; g < 3; ++g) boffg[g] = ((g << 9) + c) * HID + kb;
  const int boff_fc = c * HID + kb;

  // hoisted per-lane encoder gate weights (K=3 input matmul done inline, f32)
  float wE[3][3], biE[3], bhE[3];
#pragma unroll
  for (int g = 0; g < 3; ++g) {
    const int j = (g << 9) + c;
    wE[g][0] = enc_wih[j * 3 + 0];
    wE[g][1] = enc_wih[j * 3 + 1];
    wE[g][2] = enc_wih[j * 3 + 2];
    biE[g] = enc_bih[j];
    bhE[g] = enc_bhh[j];
  }

  __shared__ float yb[64];
  const f32x4 zf = {0.0f, 0.0f, 0.0f, 0.0f};
  int cur = 0;

  // ================= encoder: 512 steps =================
  for (int t = 0; t < SEQL; ++t) {
    f32x4 acc[2][3];
#pragma unroll
    for (int r = 0; r < 2; ++r)
#pragma unroll
      for (int g = 0; g < 3; ++g) acc[r][g] = zf;

    const float* hp = cur ? hfB : hfA;
    float* hn = cur ? hfA : hfB;
    __bf16* nhi = cur ? hhA : hhB;
    __bf16* nlo = cur ? hlA : hlB;

    if (t != 0) {
      const __bf16* Ah = cur ? hhB : hhA;
      const __bf16* Al = cur ? hlB : hlA;
      gh_gemm(Ah, Al, ench_hi, ench_lo, aoff0, aoff1, boffg, acc);
    }

#pragma unroll
    for (int r = 0; r < 2; ++r) {
#pragma unroll
      for (int reg = 0; reg < 4; ++reg) {
        const int row = rowbase + (r << 4) + ((lane >> 4) << 2) + reg;
        const float* xp = src + ((size_t)t * BATCH + row) * 3;
        const float x0 = xp[0], x1 = xp[1], x2 = xp[2];
        const float gir = fmaf(x0, wE[0][0], fmaf(x1, wE[0][1], fmaf(x2, wE[0][2], biE[0])));
        const float giz = fmaf(x0, wE[1][0], fmaf(x1, wE[1][1], fmaf(x2, wE[1][2], biE[1])));
        const float gin = fmaf(x0, wE[2][0], fmaf(x1, wE[2][1], fmaf(x2, wE[2][2], biE[2])));
        const float rg = sig_(gir + acc[r][0][reg] + bhE[0]);
        const float zg = sig_(giz + acc[r][1][reg] + bhE[1]);
        const float ng = tanh_(gin + rg * (acc[r][2][reg] + bhE[2]));
        const float hprev = (t == 0) ? 0.0f : hp[row * HID + c];
        const float hv = fmaf(zg, hprev - ng, ng);  // (1-z)*n + z*h
        hn[row * HID + c] = hv;
        const __bf16 hb = (__bf16)hv;
        nhi[row * HID + c] = hb;
        nlo[row * HID + c] = (__bf16)(hv - (float)hb);
      }
    }
    grid.sync();
    cur ^= 1;
  }

  // hoisted decoder gate weights (K=1 input matmul inline)
  float wD[3], biD[3], bhD[3];
#pragma unroll
  for (int g = 0; g < 3; ++g) {
    const int j = (g << 9) + c;
    wD[g] = dec_wih[j];
    biD[g] = dec_bih[j];
    bhD[g] = dec_bhh[j];
  }
  const float b1c = b1[c];
  const float b2v = b2[0];
  int H = hor[0];
  if (H < 1 || H > 96) H = 96;  // defensive

  // ================= decoder: H steps, 2 phases each =================
  for (int t = 0; t < H; ++t) {
    // ---- phase 1: y(t-1) reduction + GRU gates ----
    float din[2][4];
    if (t == 0) {
#pragma unroll
      for (int r = 0; r < 2; ++r)
#pragma unroll
        for (int reg = 0; reg < 4; ++reg) {
          const int row = rowbase + (r << 4) + ((lane >> 4) << 2) + reg;
          din[r][reg] = src[((size_t)(SEQL - 1) * BATCH + row) * 3];
        }
    } else {
      // each wave reduces 16 rows of fc1 against w2 (y = fc1 @ w2^T + b2)
#pragma unroll 2
      for (int rr = 0; rr < 16; ++rr) {
        const int row = rt * 64 + wv * 16 + rr;
        const float* fp = fc1 + row * HID;
        float s = 0.0f;
#pragma unroll
        for (int j = 0; j < 8; ++j) {
          const int idx = lane + (j << 6);
          s = fmaf(fp[idx], w2[idx], s);
        }
#pragma unroll
        for (int off = 1; off < 64; off <<= 1) s += __shfl_xor(s, off, 64);
        if (lane == 0) yb[wv * 16 + rr] = s + b2v;
      }
      __syncthreads();
      if (ct == 0 && tid < 64) out[(size_t)(t - 1) * BATCH + rt * 64 + tid] = yb[tid];
#pragma unroll
      for (int r = 0; r < 2; ++r)
#pragma unroll
        for (int reg = 0; reg < 4; ++reg) {
          const int row = rowbase + (r << 4) + ((lane >> 4) << 2) + reg;
          din[r][reg] = yb[row - rt * 64];
        }
    }

    f32x4 acc[2][3];
#pragma unroll
    for (int r = 0; r < 2; ++r)
#pragma unroll
      for (int g = 0; g < 3; ++g) acc[r][g] = zf;
    {
      const __bf16* Ah = cur ? hhB : hhA;
      const __bf16* Al = cur ? hlB : hlA;
      gh_gemm(Ah, Al, dech_hi, dech_lo, aoff0, aoff1, boffg, acc);
    }
    {
      const float* hp = cur ? hfB : hfA;
      float* hn = cur ? hfA : hfB;
      __bf16* nhi = cur ? hhA : hhB;
      __bf16* nlo = cur ? hlA : hlB;
#pragma unroll
      for (int r = 0; r < 2; ++r) {
#pragma unroll
        for (int reg = 0; reg < 4; ++reg) {
          const int row = rowbase + (r << 4) + ((lane >> 4) << 2) + reg;
          const float d = din[r][reg];
          const float rg = sig_(fmaf(d, wD[0], biD[0]) + acc[r][0][reg] + bhD[0]);
          const float zg = sig_(fmaf(d, wD[1], biD[1]) + acc[r][1][reg] + bhD[1]);
          const float ng = tanh_(fmaf(d, wD[2], biD[2]) + rg * (acc[r][2][reg] + bhD[2]));
          const float hprev = hp[row * HID + c];
          const float hv = fmaf(zg, hprev - ng, ng);
          hn[row * HID + c] = hv;
          const __bf16 hb = (__bf16)hv;
          nhi[row * HID + c] = hb;
          nlo[row * HID + c] = (__bf16)(hv - (float)hb);
        }
      }
    }
    grid.sync();
    cur ^= 1;

    // ---- phase 2: fc1 = relu(h @ w1^T + b1) ----
    {
      f32x4 fa0 = zf, fa1 = zf;
      const __bf16* Ah = cur ? hhB : hhA;
      const __bf16* Al = cur ? hlB : hlA;
#pragma unroll 4
      for (int kc = 0; kc < 16; ++kc) {
        const int ko = kc * 32;
        bf16x8 a0h = *(const bf16x8*)(Ah + aoff0 + ko);
        bf16x8 a0l = *(const bf16x8*)(Al + aoff0 + ko);
        bf16x8 a1h = *(const bf16x8*)(Ah + aoff1 + ko);
        bf16x8 a1l = *(const bf16x8*)(Al + aoff1 + ko);
        bf16x8 bh = *(const bf16x8*)(w1h + boff_fc + ko);
        bf16x8 bl = *(const bf16x8*)(w1l + boff_fc + ko);
        fa0 = mfma16(a0h, bh, fa0);
        fa0 = mfma16(a0l, bh, fa0);
        fa0 = mfma16(a0h, bl, fa0);
        fa1 = mfma16(a1h, bh, fa1);
        fa1 = mfma16(a1l, bh, fa1);
        fa1 = mfma16(a1h, bl, fa1);
      }
#pragma unroll
      for (int r = 0; r < 2; ++r) {
        const f32x4 fa = r ? fa1 : fa0;
#pragma unroll
        for (int reg = 0; reg < 4; ++reg) {
          const int row = rowbase + (r << 4) + ((lane >> 4) << 2) + reg;
          fc1[row * HID + c] = fmaxf(fa[reg] + b1c, 0.0f);
        }
      }
    }
    grid.sync();
  }

  // ---- final y for t = H-1 ----
  if (ct == 0) {
#pragma unroll 2
    for (int rr = 0; rr < 16; ++rr) {
      const int row = rt * 64 + wv * 16 + rr;
      const float* fp = fc1 + row * HID;
      float s = 0.0f;
#pragma unroll
      for (int j = 0; j < 8; ++j) {
        const int idx = lane + (j << 6);
        s = fmaf(fp[idx], w2[idx], s);
      }
#pragma unroll
      for (int off = 1; off < 64; off <<= 1) s += __shfl_xor(s, off, 64);
      if (lane == 0) yb[wv * 16 + rr] = s + b2v;
    }
    __syncthreads();
    if (tid < 64) out[(size_t)(H - 1) * BATCH + rt * 64 + tid] = yb[tid];
  }
}

extern "C" void kernel_launch(void* const* d_in, const int* in_sizes, int n_in,
                              void* d_out, int out_size, void* d_ws, size_t ws_size,
                              hipStream_t stream) {
  if (ws_size < WS_NEED) return;  // fail visibly rather than corrupt

  const float* src = (const float*)d_in[0];
  const float* enc_wih = (const float*)d_in[1];
  const float* enc_whh = (const float*)d_in[2];
  const float* enc_bih = (const float*)d_in[3];
  const float* enc_bhh = (const float*)d_in[4];
  const float* dec_wih = (const float*)d_in[5];
  const float* dec_whh = (const float*)d_in[6];
  const float* dec_bih = (const float*)d_in[7];
  const float* dec_bhh = (const float*)d_in[8];
  const float* w1 = (const float*)d_in[9];
  const float* b1 = (const float*)d_in[10];
  const float* w2 = (const float*)d_in[11];
  const float* b2 = (const float*)d_in[12];
  const int* hor = (const int*)d_in[13];
  float* out = (float*)d_out;
  char* ws = (char*)d_ws;

  __bf16* ench_hi = (__bf16*)(ws + OFF_ENH);
  __bf16* ench_lo = (__bf16*)(ws + OFF_ENL);
  __bf16* dech_hi = (__bf16*)(ws + OFF_DEH);
  __bf16* dech_lo = (__bf16*)(ws + OFF_DEL);
  __bf16* w1h = (__bf16*)(ws + OFF_W1H);
  __bf16* w1l = (__bf16*)(ws + OFF_W1L);

  split_w<<<dim3(3072), dim3(256), 0, stream>>>(enc_whh, ench_hi, ench_lo, 786432);
  split_w<<<dim3(3072), dim3(256), 0, stream>>>(dec_whh, dech_hi, dech_lo, 786432);
  split_w<<<dim3(1024), dim3(256), 0, stream>>>(w1, w1h, w1l, 262144);

  void* args[] = {&src, &enc_wih, &enc_bih, &enc_bhh, &dec_wih, &dec_bih, &dec_bhh,
                  &b1, &w2, &b2, &hor, &out, &ws};
  hipLaunchCooperativeKernel((void*)seq2seq_main, dim3(NWG), dim3(NTHR), args, 0, stream);
}

// Round 4
// 18335.622 us; speedup vs baseline: 2.0264x; 2.0264x over previous
//
#include <hip/hip_runtime.h>

typedef __bf16 bf16x8 __attribute__((ext_vector_type(8)));
typedef float f32x4 __attribute__((ext_vector_type(4)));

#define HID 512
#define BATCH 1024
#define SEQL 512
#define NWG 256
#define NTHR 256

// ---- workspace layout (byte offsets) ----
#define OFF_ENH 0u          // enc_whh hi : 1536*512*2
#define OFF_ENL 1572864u
#define OFF_DEH 3145728u
#define OFF_DEL 4718592u
#define OFF_W1H 6291456u    // w1 hi : 512*512*2
#define OFF_W1L 6815744u
#define OFF_HP0 7340032u    // packed h (bf16 hi | lo<<16) u32 [1024][512] = 2MB
#define OFF_HP1 9437184u
#define OFF_FC1 11534336u   // fc1 f32 : 2MB
#define OFF_BAR 13631488u   // 16 group counters, 256B stride
#define WS_NEED 13635584u

// LDS = 64KB exactly (sharedMemPerBlock limit): hi half-plane [64][256]bf16 (32KB)
// at 0, lo half-plane at 32768. One K-half (256 cols) staged at a time.
// yb aliases sm[0..255] (only live between y-reduce and next stage, sync-separated).
#define LDS_LO 32768
#define SWZ(row, cb) (((row) << 9) + ((cb) ^ (((row) & 7) << 4)))

__device__ __forceinline__ f32x4 mfma16(bf16x8 a, bf16x8 b, f32x4 c) {
  return __builtin_amdgcn_mfma_f32_16x16x32_bf16(a, b, c, 0, 0, 0);
}
__device__ __forceinline__ float sig_(float x) { return 1.0f / (1.0f + __expf(-x)); }
__device__ __forceinline__ float tanh_(float x) { return 1.0f - 2.0f / (__expf(2.0f * x) + 1.0f); }

// Agent-scope relaxed atomics: bypass L1/L2 to the coherent point (L3).
// Correct regardless of WG->XCD placement; never invalidates caches.
__device__ __forceinline__ unsigned long long ald64(const void* p) {
  return __hip_atomic_load((const unsigned long long*)p, __ATOMIC_RELAXED,
                           __HIP_MEMORY_SCOPE_AGENT);
}
__device__ __forceinline__ void ast32(void* p, unsigned v) {
  __hip_atomic_store((unsigned*)p, v, __ATOMIC_RELAXED, __HIP_MEMORY_SCOPE_AGENT);
}
__device__ __forceinline__ void astf(void* p, float v) {
  __hip_atomic_store((float*)p, v, __ATOMIC_RELAXED, __HIP_MEMORY_SCOPE_AGENT);
}

__global__ void split_w(const float* __restrict__ a, __bf16* __restrict__ hi,
                        __bf16* __restrict__ lo, int n) {
  int i = blockIdx.x * blockDim.x + threadIdx.x;
  if (i < n) {
    float v = a[i];
    __bf16 h = (__bf16)v;
    hi[i] = h;
    lo[i] = (__bf16)(v - (float)h);
  }
}

// 16-WG group barrier. __syncthreads() drains vmcnt before s_barrier, so all of
// this WG's (write-through atomic) stores are at the coherent point before the
// arrival add. BOUNDED spin: a bug yields a finite wrong answer, never a hang.
__device__ __forceinline__ void gbar(unsigned* cnt, unsigned target) {
  __syncthreads();
  if (threadIdx.x == 0) {
    __hip_atomic_fetch_add(cnt, 1u, __ATOMIC_RELAXED, __HIP_MEMORY_SCOPE_AGENT);
    int i = 0;
    while (__hip_atomic_load(cnt, __ATOMIC_RELAXED, __HIP_MEMORY_SCOPE_AGENT) < target) {
      __builtin_amdgcn_s_sleep(2);
      if (++i >= 20000) break;  // ~ms-scale cap
    }
  }
  __syncthreads();
  __builtin_amdgcn_sched_barrier(0);
}

// Stage one K-half (64 rows x 256 cols) of packed h -> LDS hi/lo planes.
// Thread tid owns col-pair (2*(tid&127), +1) of the half for 32 rows ((tid>>7)*32..).
__device__ __forceinline__ void stage_half(char* sm, const unsigned* hsrc, int row0,
                                           int khalf, int tid) {
  const int cp = tid & 127;
  const int rh = (tid >> 7) << 5;
  const unsigned long long* src = (const unsigned long long*)hsrc +
                                  ((size_t)(row0 + rh) << 8) + (khalf << 7) + cp;
  unsigned long long b0[16], b1[16];
#pragma unroll
  for (int j = 0; j < 16; ++j) b0[j] = ald64(src + (size_t)j * 256);
#pragma unroll
  for (int j = 0; j < 16; ++j) b1[j] = ald64(src + (size_t)(16 + j) * 256);
  auto PR = [&](unsigned long long(&b)[16], int r0) {
#pragma unroll
    for (int j = 0; j < 16; ++j) {
      const int row = rh + r0 + j;
      const unsigned p0 = (unsigned)b[j];          // col 2cp   : hi | lo<<16
      const unsigned p1 = (unsigned)(b[j] >> 32);  // col 2cp+1
      const unsigned hw = (p0 & 0xffffu) | (p1 << 16);
      const unsigned lw = (p0 >> 16) | (p1 & 0xffff0000u);
      const int sa = SWZ(row, cp << 2);
      *(unsigned*)(sm + sa) = hw;
      *(unsigned*)(sm + LDS_LO + sa) = lw;
    }
  };
  PR(b0, 0);
  PR(b1, 16);
}

// gates GEMM over one K-half (8 k-chunks of 32): 6 col-frags, bf16 hi/lo 3-pass.
__device__ __forceinline__ void gh6h(const char* sm, int rl, int kbb, int khalf,
                                     const __bf16* __restrict__ Bh,
                                     const __bf16* __restrict__ Bl,
                                     const int (&boff)[6], f32x4 (&acc)[6]) {
#pragma unroll 4
  for (int kc = 0; kc < 8; ++kc) {
    const int sa = SWZ(rl, (kc << 6) + kbb);
    bf16x8 ah = *(const bf16x8*)(sm + sa);
    bf16x8 al = *(const bf16x8*)(sm + LDS_LO + sa);
    const int ko = (khalf << 8) + (kc << 5);
#pragma unroll
    for (int f = 0; f < 6; ++f) {
      bf16x8 bh = *(const bf16x8*)(Bh + boff[f] + ko);
      bf16x8 bl = *(const bf16x8*)(Bl + boff[f] + ko);
      acc[f] = mfma16(ah, bh, acc[f]);
      acc[f] = mfma16(al, bh, acc[f]);
      acc[f] = mfma16(ah, bl, acc[f]);
    }
  }
}

__device__ __forceinline__ void gh2h(const char* sm, int rl, int kbb, int khalf,
                                     const __bf16* __restrict__ Bh,
                                     const __bf16* __restrict__ Bl,
                                     const int (&boff)[2], f32x4 (&acc)[2]) {
#pragma unroll 4
  for (int kc = 0; kc < 8; ++kc) {
    const int sa = SWZ(rl, (kc << 6) + kbb);
    bf16x8 ah = *(const bf16x8*)(sm + sa);
    bf16x8 al = *(const bf16x8*)(sm + LDS_LO + sa);
    const int ko = (khalf << 8) + (kc << 5);
#pragma unroll
    for (int f = 0; f < 2; ++f) {
      bf16x8 bh = *(const bf16x8*)(Bh + boff[f] + ko);
      bf16x8 bl = *(const bf16x8*)(Bl + boff[f] + ko);
      acc[f] = mfma16(ah, bh, acc[f]);
      acc[f] = mfma16(al, bh, acc[f]);
      acc[f] = mfma16(ah, bl, acc[f]);
    }
  }
}

__global__ void __launch_bounds__(NTHR, 1) seq2seq_main(
    const float* __restrict__ src, const float* __restrict__ enc_wih,
    const float* __restrict__ enc_bih, const float* __restrict__ enc_bhh,
    const float* __restrict__ dec_wih, const float* __restrict__ dec_bih,
    const float* __restrict__ dec_bhh, const float* __restrict__ b1,
    const float* __restrict__ w2, const float* __restrict__ b2,
    const int* __restrict__ hor, float* __restrict__ out, char* __restrict__ ws) {
  __shared__ f32x4 smv[4096];  // 65536 B exactly
  char* sm = (char*)smv;
  float* yb = (float*)sm;  // aliased (see layout note)

  const __bf16* ench_hi = (const __bf16*)(ws + OFF_ENH);
  const __bf16* ench_lo = (const __bf16*)(ws + OFF_ENL);
  const __bf16* dech_hi = (const __bf16*)(ws + OFF_DEH);
  const __bf16* dech_lo = (const __bf16*)(ws + OFF_DEL);
  const __bf16* w1h = (const __bf16*)(ws + OFF_W1H);
  const __bf16* w1l = (const __bf16*)(ws + OFF_W1L);
  unsigned* hp0 = (unsigned*)(ws + OFF_HP0);
  unsigned* hp1 = (unsigned*)(ws + OFF_HP1);
  float* fc1 = (float*)(ws + OFF_FC1);

  // group g owns batch rows [64g, 64g+64); members bid ≡ g (mod 8) for XCD
  // affinity under round-robin dispatch (perf heuristic only, never correctness).
  const int bid = blockIdx.x;
  const int g = (bid & 7) + ((bid >> 7) << 3);
  const int ct = (bid >> 3) & 15;  // 32-col slice
  const int tid = threadIdx.x;
  const int wv = tid >> 6;
  const int lane = tid & 63;
  const int lan15 = lane & 15;
  const int crow = (lane >> 4) << 2;  // C-layout row group
  const int kbe = (lane >> 4) << 3;   // element k-offset in fragment
  const int kbb = kbe << 1;           // byte k-offset
  const int rl = (wv << 4) + lan15;   // LDS A-row for this lane (wave = 16 rows)
  const int row0 = g << 6;

  unsigned* cnt = (unsigned*)(ws + OFF_BAR) + (g << 6);  // 256B stride per group

  int boff[6];
#pragma unroll
  for (int gg = 0; gg < 3; ++gg)
#pragma unroll
    for (int ch = 0; ch < 2; ++ch)
      boff[gg * 2 + ch] = ((gg << 9) + (ct << 5) + (ch << 4) + lan15) * HID + kbe;
  int bofffc[2];
#pragma unroll
  for (int ch = 0; ch < 2; ++ch) bofffc[ch] = ((ct << 5) + (ch << 4) + lan15) * HID + kbe;

  // hoisted per-lane encoder gate params (input matmul K=3 inline, f32)
  float wE[2][3][3], biE[2][3], bhE[2][3];
#pragma unroll
  for (int ch = 0; ch < 2; ++ch)
#pragma unroll
    for (int gg = 0; gg < 3; ++gg) {
      const int j = (gg << 9) + (ct << 5) + (ch << 4) + lan15;
      wE[ch][gg][0] = enc_wih[j * 3 + 0];
      wE[ch][gg][1] = enc_wih[j * 3 + 1];
      wE[ch][gg][2] = enc_wih[j * 3 + 2];
      biE[ch][gg] = enc_bih[j];
      bhE[ch][gg] = enc_bhh[j];
    }

  const f32x4 zf = {0.0f, 0.0f, 0.0f, 0.0f};
  float hpv[2][4] = {{0.f, 0.f, 0.f, 0.f}, {0.f, 0.f, 0.f, 0.f}};

  // ================= encoder: 512 steps =================
  for (int t = 0; t < SEQL; ++t) {
    f32x4 acc[6];
#pragma unroll
    for (int f = 0; f < 6; ++f) acc[f] = zf;

    if (t != 0) {
      const unsigned* hsrc = (t & 1) ? hp1 : hp0;  // h_t lives in plane t&1
      stage_half(sm, hsrc, row0, 0, tid);
      __syncthreads();
      gh6h(sm, rl, kbb, 0, ench_hi, ench_lo, boff, acc);
      __syncthreads();
      stage_half(sm, hsrc, row0, 1, tid);
      __syncthreads();
      gh6h(sm, rl, kbb, 1, ench_hi, ench_lo, boff, acc);
    }

    unsigned* hn = ((t + 1) & 1) ? hp1 : hp0;
#pragma unroll
    for (int reg = 0; reg < 4; ++reg) {
      const int row = row0 + (wv << 4) + crow + reg;
      const float* xp = src + ((size_t)t * BATCH + row) * 3;
      const float x0 = xp[0], x1 = xp[1], x2 = xp[2];
#pragma unroll
      for (int ch = 0; ch < 2; ++ch) {
        const float gir =
            fmaf(x0, wE[ch][0][0], fmaf(x1, wE[ch][0][1], fmaf(x2, wE[ch][0][2], biE[ch][0])));
        const float giz =
            fmaf(x0, wE[ch][1][0], fmaf(x1, wE[ch][1][1], fmaf(x2, wE[ch][1][2], biE[ch][1])));
        const float gin =
            fmaf(x0, wE[ch][2][0], fmaf(x1, wE[ch][2][1], fmaf(x2, wE[ch][2][2], biE[ch][2])));
        const float rg = sig_(gir + acc[ch][reg] + bhE[ch][0]);
        const float zg = sig_(giz + acc[2 + ch][reg] + bhE[ch][1]);
        const float ng = tanh_(gin + rg * (acc[4 + ch][reg] + bhE[ch][2]));
        const float hv = fmaf(zg, hpv[ch][reg] - ng, ng);  // (1-z)*n + z*h
        hpv[ch][reg] = hv;
        const __bf16 hb = (__bf16)hv;
        const __bf16 lb = (__bf16)(hv - (float)hb);
        const unsigned pw = (unsigned)__builtin_bit_cast(unsigned short, hb) |
                            ((unsigned)__builtin_bit_cast(unsigned short, lb) << 16);
        ast32(hn + (size_t)row * HID + (ct << 5) + (ch << 4) + lan15, pw);
      }
    }
    gbar(cnt, 16u * (unsigned)(t + 1));
  }

  // ================= decoder =================
  float wD[2][3], biD[2][3], bhD[2][3], b1c[2];
#pragma unroll
  for (int ch = 0; ch < 2; ++ch) {
#pragma unroll
    for (int gg = 0; gg < 3; ++gg) {
      const int j = (gg << 9) + (ct << 5) + (ch << 4) + lan15;
      wD[ch][gg] = dec_wih[j];
      biD[ch][gg] = dec_bih[j];
      bhD[ch][gg] = dec_bhh[j];
    }
    b1c[ch] = b1[(ct << 5) + (ch << 4) + lan15];
  }
  const float b2v = b2[0];
  float w2p0[4], w2p1[4];
#pragma unroll
  for (int j = 0; j < 4; ++j) {
    w2p0[j] = w2[2 * (lane + j * 64)];
    w2p1[j] = w2[2 * (lane + j * 64) + 1];
  }
  int H = hor[0];
  if (H < 1 || H > 96) H = 96;

  for (int t = 0; t < H; ++t) {
    // ---- phase 1: y(t-1) + GRU gates ----
    float din[4];
    if (t == 0) {
#pragma unroll
      for (int reg = 0; reg < 4; ++reg) {
        const int row = row0 + (wv << 4) + crow + reg;
        din[reg] = src[((size_t)(SEQL - 1) * BATCH + row) * 3];
      }
    } else {
#pragma unroll 2
      for (int rr = 0; rr < 16; ++rr) {
        const int row = row0 + (wv << 4) + rr;
        const unsigned long long* fp = (const unsigned long long*)fc1 + ((size_t)row << 8);
        float s = 0.0f;
#pragma unroll
        for (int j = 0; j < 4; ++j) {
          const unsigned long long w = ald64(fp + lane + (j << 6));
          const float f0 = __builtin_bit_cast(float, (unsigned)(w & 0xffffffffULL));
          const float f1 = __builtin_bit_cast(float, (unsigned)(w >> 32));
          s = fmaf(f0, w2p0[j], fmaf(f1, w2p1[j], s));
        }
#pragma unroll
        for (int off = 1; off < 64; off <<= 1) s += __shfl_xor(s, off, 64);
        if (lane == 0) yb[(wv << 4) + rr] = s + b2v;
      }
      __syncthreads();
      if (ct == 0 && tid < 64) out[(size_t)(t - 1) * BATCH + row0 + tid] = yb[tid];
#pragma unroll
      for (int reg = 0; reg < 4; ++reg) din[reg] = yb[(wv << 4) + crow + reg];
      __syncthreads();  // yb dead before stage_half overwrites sm[0..]
    }

    {
      const unsigned* hsrc = (t & 1) ? hp1 : hp0;  // dec h_t in plane t&1
      f32x4 acc[6];
#pragma unroll
      for (int f = 0; f < 6; ++f) acc[f] = zf;
      stage_half(sm, hsrc, row0, 0, tid);
      __syncthreads();
      gh6h(sm, rl, kbb, 0, dech_hi, dech_lo, boff, acc);
      __syncthreads();
      stage_half(sm, hsrc, row0, 1, tid);
      __syncthreads();
      gh6h(sm, rl, kbb, 1, dech_hi, dech_lo, boff, acc);

      unsigned* hn = ((t + 1) & 1) ? hp1 : hp0;
#pragma unroll
      for (int reg = 0; reg < 4; ++reg) {
        const int row = row0 + (wv << 4) + crow + reg;
        const float d = din[reg];
#pragma unroll
        for (int ch = 0; ch < 2; ++ch) {
          const float rg = sig_(fmaf(d, wD[ch][0], biD[ch][0]) + acc[ch][reg] + bhD[ch][0]);
          const float zg = sig_(fmaf(d, wD[ch][1], biD[ch][1]) + acc[2 + ch][reg] + bhD[ch][1]);
          const float ng =
              tanh_(fmaf(d, wD[ch][2], biD[ch][2]) + rg * (acc[4 + ch][reg] + bhD[ch][2]));
          const float hv = fmaf(zg, hpv[ch][reg] - ng, ng);
          hpv[ch][reg] = hv;
          const __bf16 hb = (__bf16)hv;
          const __bf16 lb = (__bf16)(hv - (float)hb);
          const unsigned pw = (unsigned)__builtin_bit_cast(unsigned short, hb) |
                              ((unsigned)__builtin_bit_cast(unsigned short, lb) << 16);
          ast32(hn + (size_t)row * HID + (ct << 5) + (ch << 4) + lan15, pw);
        }
      }
    }
    gbar(cnt, 16u * (unsigned)(SEQL + 2 * t + 1));

    // ---- phase 2: fc1 = relu(h @ w1^T + b1) ----
    {
      const unsigned* hsrc = ((t + 1) & 1) ? hp1 : hp0;
      f32x4 fa[2];
      fa[0] = zf;
      fa[1] = zf;
      stage_half(sm, hsrc, row0, 0, tid);
      __syncthreads();
      gh2h(sm, rl, kbb, 0, w1h, w1l, bofffc, fa);
      __syncthreads();
      stage_half(sm, hsrc, row0, 1, tid);
      __syncthreads();
      gh2h(sm, rl, kbb, 1, w1h, w1l, bofffc, fa);
#pragma unroll
      for (int reg = 0; reg < 4; ++reg) {
        const int row = row0 + (wv << 4) + crow + reg;
#pragma unroll
        for (int ch = 0; ch < 2; ++ch) {
          astf(&fc1[(size_t)row * HID + (ct << 5) + (ch << 4) + lan15],
               fmaxf(fa[ch][reg] + b1c[ch], 0.0f));
        }
      }
    }
    gbar(cnt, 16u * (unsigned)(SEQL + 2 * t + 2));
  }

  // ---- final y for t = H-1 ----
  if (ct == 0) {
#pragma unroll 2
    for (int rr = 0; rr < 16; ++rr) {
      const int row = row0 + (wv << 4) + rr;
      const unsigned long long* fp = (const unsigned long long*)fc1 + ((size_t)row << 8);
      float s = 0.0f;
#pragma unroll
      for (int j = 0; j < 4; ++j) {
        const unsigned long long w = ald64(fp + lane + (j << 6));
        const float f0 = __builtin_bit_cast(float, (unsigned)(w & 0xffffffffULL));
        const float f1 = __builtin_bit_cast(float, (unsigned)(w >> 32));
        s = fmaf(f0, w2p0[j], fmaf(f1, w2p1[j], s));
      }
#pragma unroll
      for (int off = 1; off < 64; off <<= 1) s += __shfl_xor(s, off, 64);
      if (lane == 0) yb[(wv << 4) + rr] = s + b2v;
    }
    __syncthreads();
    if (tid < 64) out[(size_t)(H - 1) * BATCH + row0 + tid] = yb[tid];
  }
}

extern "C" void kernel_launch(void* const* d_in, const int* in_sizes, int n_in,
                              void* d_out, int out_size, void* d_ws, size_t ws_size,
                              hipStream_t stream) {
  if (ws_size < WS_NEED) return;

  const float* src = (const float*)d_in[0];
  const float* enc_wih = (const float*)d_in[1];
  const float* enc_whh = (const float*)d_in[2];
  const float* enc_bih = (const float*)d_in[3];
  const float* enc_bhh = (const float*)d_in[4];
  const float* dec_wih = (const float*)d_in[5];
  const float* dec_whh = (const float*)d_in[6];
  const float* dec_bih = (const float*)d_in[7];
  const float* dec_bhh = (const float*)d_in[8];
  const float* w1 = (const float*)d_in[9];
  const float* b1 = (const float*)d_in[10];
  const float* w2 = (const float*)d_in[11];
  const float* b2 = (const float*)d_in[12];
  const int* hor = (const int*)d_in[13];
  float* out = (float*)d_out;
  char* ws = (char*)d_ws;

  hipMemsetAsync(ws + OFF_BAR, 0, 4096, stream);  // zero barrier counters every call

  split_w<<<dim3(3072), dim3(256), 0, stream>>>(enc_whh, (__bf16*)(ws + OFF_ENH),
                                                (__bf16*)(ws + OFF_ENL), 786432);
  split_w<<<dim3(3072), dim3(256), 0, stream>>>(dec_whh, (__bf16*)(ws + OFF_DEH),
                                                (__bf16*)(ws + OFF_DEL), 786432);
  split_w<<<dim3(1024), dim3(256), 0, stream>>>(w1, (__bf16*)(ws + OFF_W1H),
                                                (__bf16*)(ws + OFF_W1L), 262144);

  void* args[] = {&src, &enc_wih, &enc_bih, &enc_bhh, &dec_wih, &dec_bih, &dec_bhh,
                  &b1, &w2, &b2, &hor, &out, &ws};
  hipLaunchCooperativeKernel((void*)seq2seq_main, dim3(NWG), dim3(NTHR), args, 0, stream);
}

// Round 5
// 16292.029 us; speedup vs baseline: 2.2806x; 1.1254x over previous
//
#include <hip/hip_runtime.h>

typedef __bf16 bf16x8 __attribute__((ext_vector_type(8)));
typedef float f32x4 __attribute__((ext_vector_type(4)));

#define HID 512
#define BATCH 1024
#define SEQL 512
#define NWG 256
#define NTHR 512

// ---- workspace layout (byte offsets) ----
#define OFF_ENH 0u          // enc_whh hi : 1536*512*2
#define OFF_ENL 1572864u
#define OFF_DEH 3145728u
#define OFF_DEL 4718592u
#define OFF_W1H 6291456u    // w1 hi : 512*512*2
#define OFF_W1L 6815744u
#define OFF_HP0 7340032u    // packed h (bf16 hi | lo<<16) u32 [1024][512] = 2MB
#define OFF_HP1 9437184u
#define OFF_FC1 11534336u   // fc1 f32 : 2MB
#define OFF_BAR 13631488u   // 32 group counters, 128B stride = 4KB
#define WS_NEED 13635584u

// LDS = 64KB exactly: A-tile hi plane [32][512]bf16 (32KB) at 0, lo at 32768.
// yb aliases sm[0..127] (only live between y-reduce and next stage, sync-separated).
#define LDS_LO 32768
#define SWZ(row, cb) (((row) << 10) + ((cb) ^ (((row) & 7) << 4)))

__device__ __forceinline__ f32x4 mfma16(bf16x8 a, bf16x8 b, f32x4 c) {
  return __builtin_amdgcn_mfma_f32_16x16x32_bf16(a, b, c, 0, 0, 0);
}
__device__ __forceinline__ float sig_(float x) { return 1.0f / (1.0f + __expf(-x)); }
__device__ __forceinline__ float tanh_(float x) { return 1.0f - 2.0f / (__expf(2.0f * x) + 1.0f); }

// Agent-scope relaxed atomics: bypass L1/L2 to the coherent point (L3).
// Correct regardless of WG->XCD placement; never invalidates caches.
__device__ __forceinline__ unsigned long long ald64(const void* p) {
  return __hip_atomic_load((const unsigned long long*)p, __ATOMIC_RELAXED,
                           __HIP_MEMORY_SCOPE_AGENT);
}
__device__ __forceinline__ void ast32(void* p, unsigned v) {
  __hip_atomic_store((unsigned*)p, v, __ATOMIC_RELAXED, __HIP_MEMORY_SCOPE_AGENT);
}
__device__ __forceinline__ void astf(void* p, float v) {
  __hip_atomic_store((float*)p, v, __ATOMIC_RELAXED, __HIP_MEMORY_SCOPE_AGENT);
}

__global__ void split_w(const float* __restrict__ a, __bf16* __restrict__ hi,
                        __bf16* __restrict__ lo, int n) {
  int i = blockIdx.x * blockDim.x + threadIdx.x;
  if (i < n) {
    float v = a[i];
    __bf16 h = (__bf16)v;
    hi[i] = h;
    lo[i] = (__bf16)(v - (float)h);
  }
}

// 8-WG group barrier. __syncthreads() drains vmcnt before s_barrier, so all of
// this WG's write-through atomic stores are at the coherent point before the
// arrival add. BOUNDED spin: a bug yields a finite wrong answer, never a hang.
__device__ __forceinline__ void gbar(unsigned* cnt, unsigned target) {
  __syncthreads();
  if (threadIdx.x == 0) {
    __hip_atomic_fetch_add(cnt, 1u, __ATOMIC_RELAXED, __HIP_MEMORY_SCOPE_AGENT);
    int i = 0;
    while (__hip_atomic_load(cnt, __ATOMIC_RELAXED, __HIP_MEMORY_SCOPE_AGENT) < target) {
      __builtin_amdgcn_s_sleep(2);
      if (++i >= 30000) break;  // ~ms-scale cap
    }
  }
  __syncthreads();
  __builtin_amdgcn_sched_barrier(0);
}

// Stage the group's 32 rows x 512 cols packed-h tile -> LDS hi/lo planes.
// Thread tid owns u64 col-pair cp (cols 2cp, 2cp+1) for 16 rows ((tid>>8)*16..).
__device__ __forceinline__ void stage_h32(char* sm, const unsigned* hsrc, int row0, int tid) {
  const int cp = tid & 255;
  const int rh = (tid >> 8) << 4;
  const unsigned long long* src =
      (const unsigned long long*)hsrc + ((size_t)(row0 + rh) << 8) + cp;
  unsigned long long b[16];
#pragma unroll
  for (int j = 0; j < 16; ++j) b[j] = ald64(src + (size_t)j * 256);
#pragma unroll
  for (int j = 0; j < 16; ++j) {
    const int row = rh + j;
    const unsigned p0 = (unsigned)b[j];          // col 2cp   : hi | lo<<16
    const unsigned p1 = (unsigned)(b[j] >> 32);  // col 2cp+1
    const unsigned hw = (p0 & 0xffffu) | (p1 << 16);
    const unsigned lw = (p0 >> 16) | (p1 & 0xffff0000u);
    const int sa = SWZ(row, cp << 2);
    *(unsigned*)(sm + sa) = hw;
    *(unsigned*)(sm + LDS_LO + sa) = lw;
  }
}

// gates GEMM: wave computes one 16-row x 16-col frag per gate (3 frags),
// K=512, bf16 hi/lo 3-pass. A from LDS, B (weights) from global (L2-hot).
__device__ __forceinline__ void gh3(const char* sm, int rl, int kbb,
                                    const __bf16* __restrict__ Bh,
                                    const __bf16* __restrict__ Bl,
                                    const int (&boff)[3], f32x4 (&acc)[3]) {
#pragma unroll 4
  for (int kc = 0; kc < 16; ++kc) {
    const int sa = SWZ(rl, (kc << 6) + kbb);
    bf16x8 ah = *(const bf16x8*)(sm + sa);
    bf16x8 al = *(const bf16x8*)(sm + LDS_LO + sa);
    const int ko = kc << 5;
#pragma unroll
    for (int f = 0; f < 3; ++f) {
      bf16x8 bh = *(const bf16x8*)(Bh + boff[f] + ko);
      bf16x8 bl = *(const bf16x8*)(Bl + boff[f] + ko);
      acc[f] = mfma16(ah, bh, acc[f]);
      acc[f] = mfma16(al, bh, acc[f]);
      acc[f] = mfma16(ah, bl, acc[f]);
    }
  }
}

// fc1 GEMM: one frag per wave.
__device__ __forceinline__ void gh1(const char* sm, int rl, int kbb,
                                    const __bf16* __restrict__ Bh,
                                    const __bf16* __restrict__ Bl, int boff, f32x4& acc) {
#pragma unroll 4
  for (int kc = 0; kc < 16; ++kc) {
    const int sa = SWZ(rl, (kc << 6) + kbb);
    bf16x8 ah = *(const bf16x8*)(sm + sa);
    bf16x8 al = *(const bf16x8*)(sm + LDS_LO + sa);
    const int ko = kc << 5;
    bf16x8 bh = *(const bf16x8*)(Bh + boff + ko);
    bf16x8 bl = *(const bf16x8*)(Bl + boff + ko);
    acc = mfma16(ah, bh, acc);
    acc = mfma16(al, bh, acc);
    acc = mfma16(ah, bl, acc);
  }
}

__global__ void __launch_bounds__(NTHR, 2) seq2seq_main(
    const float* __restrict__ src, const float* __restrict__ enc_wih,
    const float* __restrict__ enc_bih, const float* __restrict__ enc_bhh,
    const float* __restrict__ dec_wih, const float* __restrict__ dec_bih,
    const float* __restrict__ dec_bhh, const float* __restrict__ b1,
    const float* __restrict__ w2, const float* __restrict__ b2,
    const int* __restrict__ hor, float* __restrict__ out, char* __restrict__ ws) {
  __shared__ f32x4 smv[4096];  // 65536 B exactly
  char* sm = (char*)smv;
  float* yb = (float*)sm;  // aliased (see layout note)

  const __bf16* ench_hi = (const __bf16*)(ws + OFF_ENH);
  const __bf16* ench_lo = (const __bf16*)(ws + OFF_ENL);
  const __bf16* dech_hi = (const __bf16*)(ws + OFF_DEH);
  const __bf16* dech_lo = (const __bf16*)(ws + OFF_DEL);
  const __bf16* w1h = (const __bf16*)(ws + OFF_W1H);
  const __bf16* w1l = (const __bf16*)(ws + OFF_W1L);
  unsigned* hp0 = (unsigned*)(ws + OFF_HP0);
  unsigned* hp1 = (unsigned*)(ws + OFF_HP1);
  float* fc1 = (float*)(ws + OFF_FC1);

  // group G (=bid>>3) owns batch rows [32G, 32G+32); member ct (=bid&7) owns
  // 64-col slice ct. Round-robin dispatch puts all WGs with slice x on XCD x,
  // so each XCD's L2 holds only 1/8 of the weights (perf heuristic only).
  const int bid = blockIdx.x;
  const int G = bid >> 3;
  const int ct = bid & 7;
  const int tid = threadIdx.x;
  const int wv = tid >> 6;
  const int lane = tid & 63;
  const int lan15 = lane & 15;
  const int crow = (lane >> 4) << 2;  // C-layout row group
  const int kbe = (lane >> 4) << 3;   // element k-offset in fragment
  const int kbb = kbe << 1;           // byte k-offset
  const int wr = wv & 1;              // row-frag (16 rows)
  const int wc = wv >> 1;             // col-frag (16 cols) within 64-col slice
  const int rl = (wr << 4) + lan15;   // LDS A-row for this lane
  const int row0 = G << 5;
  const int cg = (ct << 6) + (wc << 4) + lan15;  // this lane's hidden column

  unsigned* cnt = (unsigned*)(ws + OFF_BAR) + (G << 5);  // 128B stride per group

  int boff[3];
#pragma unroll
  for (int g = 0; g < 3; ++g) boff[g] = ((g << 9) + cg) * HID + kbe;
  const int boff_fc = cg * HID + kbe;

  // hoisted per-lane encoder gate params (input matmul K=3 inline, f32)
  float wE[3][3], biE[3], bhE[3];
#pragma unroll
  for (int g = 0; g < 3; ++g) {
    const int j = (g << 9) + cg;
    wE[g][0] = enc_wih[j * 3 + 0];
    wE[g][1] = enc_wih[j * 3 + 1];
    wE[g][2] = enc_wih[j * 3 + 2];
    biE[g] = enc_bih[j];
    bhE[g] = enc_bhh[j];
  }

  const f32x4 zf = {0.0f, 0.0f, 0.0f, 0.0f};
  float hpv[4] = {0.f, 0.f, 0.f, 0.f};

  // ================= encoder: 512 steps =================
  for (int t = 0; t < SEQL; ++t) {
    f32x4 acc[3];
#pragma unroll
    for (int f = 0; f < 3; ++f) acc[f] = zf;

    if (t != 0) {
      stage_h32(sm, (t & 1) ? hp1 : hp0, row0, tid);  // h_t lives in plane t&1
      __syncthreads();
      gh3(sm, rl, kbb, ench_hi, ench_lo, boff, acc);
    }

    unsigned* hn = ((t + 1) & 1) ? hp1 : hp0;
#pragma unroll
    for (int reg = 0; reg < 4; ++reg) {
      const int row = row0 + (wr << 4) + crow + reg;
      const float* xp = src + ((size_t)t * BATCH + row) * 3;
      const float x0 = xp[0], x1 = xp[1], x2 = xp[2];
      const float gir = fmaf(x0, wE[0][0], fmaf(x1, wE[0][1], fmaf(x2, wE[0][2], biE[0])));
      const float giz = fmaf(x0, wE[1][0], fmaf(x1, wE[1][1], fmaf(x2, wE[1][2], biE[1])));
      const float gin = fmaf(x0, wE[2][0], fmaf(x1, wE[2][1], fmaf(x2, wE[2][2], biE[2])));
      const float rg = sig_(gir + acc[0][reg] + bhE[0]);
      const float zg = sig_(giz + acc[1][reg] + bhE[1]);
      const float ng = tanh_(gin + rg * (acc[2][reg] + bhE[2]));
      const float hv = fmaf(zg, hpv[reg] - ng, ng);  // (1-z)*n + z*h
      hpv[reg] = hv;
      const __bf16 hb = (__bf16)hv;
      const __bf16 lb = (__bf16)(hv - (float)hb);
      const unsigned pw = (unsigned)__builtin_bit_cast(unsigned short, hb) |
                          ((unsigned)__builtin_bit_cast(unsigned short, lb) << 16);
      ast32(hn + (size_t)row * HID + cg, pw);
    }
    gbar(cnt, 8u * (unsigned)(t + 1));
  }

  // ================= decoder =================
  float wD[3], biD[3], bhD[3];
#pragma unroll
  for (int g = 0; g < 3; ++g) {
    const int j = (g << 9) + cg;
    wD[g] = dec_wih[j];
    biD[g] = dec_bih[j];
    bhD[g] = dec_bhh[j];
  }
  const float b1c = b1[cg];
  const float b2v = b2[0];
  float w2p0[4], w2p1[4];
#pragma unroll
  for (int j = 0; j < 4; ++j) {
    w2p0[j] = w2[2 * (lane + j * 64)];
    w2p1[j] = w2[2 * (lane + j * 64) + 1];
  }
  int H = hor[0];
  if (H < 1 || H > 96) H = 96;

  for (int t = 0; t < H; ++t) {
    // ---- phase 1: y(t-1) + GRU gates ----
    float din[4];
    if (t == 0) {
#pragma unroll
      for (int reg = 0; reg < 4; ++reg) {
        const int row = row0 + (wr << 4) + crow + reg;
        din[reg] = src[((size_t)(SEQL - 1) * BATCH + row) * 3];
      }
    } else {
      // each wave reduces 4 rows of fc1 against w2 (y = fc1 @ w2^T + b2)
#pragma unroll
      for (int rr = 0; rr < 4; ++rr) {
        const int row = row0 + (wv << 2) + rr;
        const unsigned long long* fp = (const unsigned long long*)fc1 + ((size_t)row << 8);
        float s = 0.0f;
#pragma unroll
        for (int j = 0; j < 4; ++j) {
          const unsigned long long w = ald64(fp + lane + (j << 6));
          const float f0 = __builtin_bit_cast(float, (unsigned)(w & 0xffffffffULL));
          const float f1 = __builtin_bit_cast(float, (unsigned)(w >> 32));
          s = fmaf(f0, w2p0[j], fmaf(f1, w2p1[j], s));
        }
#pragma unroll
        for (int off = 1; off < 64; off <<= 1) s += __shfl_xor(s, off, 64);
        if (lane == 0) yb[(wv << 2) + rr] = s + b2v;
      }
      __syncthreads();
      if (ct == 0 && tid < 32) out[(size_t)(t - 1) * BATCH + row0 + tid] = yb[tid];
#pragma unroll
      for (int reg = 0; reg < 4; ++reg) din[reg] = yb[(wr << 4) + crow + reg];
      __syncthreads();  // yb dead before stage_h32 overwrites sm[0..]
    }

    {
      stage_h32(sm, (t & 1) ? hp1 : hp0, row0, tid);  // dec h_t in plane t&1
      __syncthreads();
      f32x4 acc[3];
#pragma unroll
      for (int f = 0; f < 3; ++f) acc[f] = zf;
      gh3(sm, rl, kbb, dech_hi, dech_lo, boff, acc);

      unsigned* hn = ((t + 1) & 1) ? hp1 : hp0;
#pragma unroll
      for (int reg = 0; reg < 4; ++reg) {
        const int row = row0 + (wr << 4) + crow + reg;
        const float d = din[reg];
        const float rg = sig_(fmaf(d, wD[0], biD[0]) + acc[0][reg] + bhD[0]);
        const float zg = sig_(fmaf(d, wD[1], biD[1]) + acc[1][reg] + bhD[1]);
        const float ng = tanh_(fmaf(d, wD[2], biD[2]) + rg * (acc[2][reg] + bhD[2]));
        const float hv = fmaf(zg, hpv[reg] - ng, ng);
        hpv[reg] = hv;
        const __bf16 hb = (__bf16)hv;
        const __bf16 lb = (__bf16)(hv - (float)hb);
        const unsigned pw = (unsigned)__builtin_bit_cast(unsigned short, hb) |
                            ((unsigned)__builtin_bit_cast(unsigned short, lb) << 16);
        ast32(hn + (size_t)row * HID + cg, pw);
      }
    }
    gbar(cnt, 8u * (unsigned)(SEQL + 2 * t + 1));

    // ---- phase 2: fc1 = relu(h @ w1^T + b1) ----
    {
      stage_h32(sm, ((t + 1) & 1) ? hp1 : hp0, row0, tid);
      __syncthreads();
      f32x4 fa = zf;
      gh1(sm, rl, kbb, w1h, w1l, boff_fc, fa);
#pragma unroll
      for (int reg = 0; reg < 4; ++reg) {
        const int row = row0 + (wr << 4) + crow + reg;
        astf(&fc1[(size_t)row * HID + cg], fmaxf(fa[reg] + b1c, 0.0f));
      }
    }
    gbar(cnt, 8u * (unsigned)(SEQL + 2 * t + 2));
  }

  // ---- final y for t = H-1 ----
  if (ct == 0) {
#pragma unroll
    for (int rr = 0; rr < 4; ++rr) {
      const int row = row0 + (wv << 2) + rr;
      const unsigned long long* fp = (const unsigned long long*)fc1 + ((size_t)row << 8);
      float s = 0.0f;
#pragma unroll
      for (int j = 0; j < 4; ++j) {
        const unsigned long long w = ald64(fp + lane + (j << 6));
        const float f0 = __builtin_bit_cast(float, (unsigned)(w & 0xffffffffULL));
        const float f1 = __builtin_bit_cast(float, (unsigned)(w >> 32));
        s = fmaf(f0, w2p0[j], fmaf(f1, w2p1[j], s));
      }
#pragma unroll
      for (int off = 1; off < 64; off <<= 1) s += __shfl_xor(s, off, 64);
      if (lane == 0) yb[(wv << 2) + rr] = s + b2v;
    }
    __syncthreads();
    if (tid < 32) out[(size_t)(H - 1) * BATCH + row0 + tid] = yb[tid];
  }
}

extern "C" void kernel_launch(void* const* d_in, const int* in_sizes, int n_in,
                              void* d_out, int out_size, void* d_ws, size_t ws_size,
                              hipStream_t stream) {
  if (ws_size < WS_NEED) return;

  const float* src = (const float*)d_in[0];
  const float* enc_wih = (const float*)d_in[1];
  const float* enc_whh = (const float*)d_in[2];
  const float* enc_bih = (const float*)d_in[3];
  const float* enc_bhh = (const float*)d_in[4];
  const float* dec_wih = (const float*)d_in[5];
  const float* dec_whh = (const float*)d_in[6];
  const float* dec_bih = (const float*)d_in[7];
  const float* dec_bhh = (const float*)d_in[8];
  const float* w1 = (const float*)d_in[9];
  const float* b1 = (const float*)d_in[10];
  const float* w2 = (const float*)d_in[11];
  const float* b2 = (const float*)d_in[12];
  const int* hor = (const int*)d_in[13];
  float* out = (float*)d_out;
  char* ws = (char*)d_ws;

  hipMemsetAsync(ws + OFF_BAR, 0, 4096, stream);  // zero barrier counters every call

  split_w<<<dim3(3072), dim3(256), 0, stream>>>(enc_whh, (__bf16*)(ws + OFF_ENH),
                                                (__bf16*)(ws + OFF_ENL), 786432);
  split_w<<<dim3(3072), dim3(256), 0, stream>>>(dec_whh, (__bf16*)(ws + OFF_DEH),
                                                (__bf16*)(ws + OFF_DEL), 786432);
  split_w<<<dim3(1024), dim3(256), 0, stream>>>(w1, (__bf16*)(ws + OFF_W1H),
                                                (__bf16*)(ws + OFF_W1L), 262144);

  void* args[] = {&src, &enc_wih, &enc_bih, &enc_bhh, &dec_wih, &dec_bih, &dec_bhh,
                  &b1, &w2, &b2, &hor, &out, &ws};
  hipLaunchCooperativeKernel((void*)seq2seq_main, dim3(NWG), dim3(NTHR), args, 0, stream);
}

// Round 6
// 16019.006 us; speedup vs baseline: 2.3195x; 1.0170x over previous
//
#include <hip/hip_runtime.h>

typedef __bf16 bf16x8 __attribute__((ext_vector_type(8)));
typedef float f32x4 __attribute__((ext_vector_type(4)));

#define HID 512
#define BATCH 1024
#define SEQL 512
#define NWG 256
#define NTHR 512

// ---- workspace layout (byte offsets) ----
#define OFF_ENH 0u          // enc_whh hi : 1536*512*2
#define OFF_ENL 1572864u
#define OFF_DEH 3145728u
#define OFF_DEL 4718592u
#define OFF_W1H 6291456u    // w1 hi : 512*512*2
#define OFF_W1L 6815744u
#define OFF_HP0 7340032u    // packed h (bf16 hi | lo<<16) u32 [1024][512] = 2MB
#define OFF_HP1 9437184u
#define OFF_FC1 11534336u   // fc1 f32 : 2MB
#define OFF_BAR 13631488u   // 32 group counters, 128B stride = 4KB (zeroed each call)
#define OFF_ASN 13635584u   // assignment area: xcd_cnt[8]@64B stride, root@512, taken[256]@1024
#define WS_NEED 13639680u

// LDS = 64KB exactly: A-tile hi plane [32][512]bf16 (32KB) at 0, lo at 32768.
// yb aliases sm[0..127]; s_pair aliases sm[0..3] (startup only; sync-separated).
#define LDS_LO 32768
#define SWZ(row, cb) (((row) << 10) + ((cb) ^ (((row) & 7) << 4)))

__device__ __forceinline__ f32x4 mfma16(bf16x8 a, bf16x8 b, f32x4 c) {
  return __builtin_amdgcn_mfma_f32_16x16x32_bf16(a, b, c, 0, 0, 0);
}
__device__ __forceinline__ float sig_(float x) { return 1.0f / (1.0f + __expf(-x)); }
__device__ __forceinline__ float tanh_(float x) { return 1.0f - 2.0f / (__expf(2.0f * x) + 1.0f); }

// Agent-scope relaxed atomics: bypass L1/L2 to the coherent point.
// Correct regardless of WG->XCD placement; never invalidates caches.
__device__ __forceinline__ unsigned long long ald64(const void* p) {
  return __hip_atomic_load((const unsigned long long*)p, __ATOMIC_RELAXED,
                           __HIP_MEMORY_SCOPE_AGENT);
}
__device__ __forceinline__ void ast32(void* p, unsigned v) {
  __hip_atomic_store((unsigned*)p, v, __ATOMIC_RELAXED, __HIP_MEMORY_SCOPE_AGENT);
}
__device__ __forceinline__ void astf(void* p, float v) {
  __hip_atomic_store((float*)p, v, __ATOMIC_RELAXED, __HIP_MEMORY_SCOPE_AGENT);
}

__global__ void split_w(const float* __restrict__ a, __bf16* __restrict__ hi,
                        __bf16* __restrict__ lo, int n) {
  int i = blockIdx.x * blockDim.x + threadIdx.x;
  if (i < n) {
    float v = a[i];
    __bf16 h = (__bf16)v;
    hi[i] = h;
    lo[i] = (__bf16)(v - (float)h);
  }
}

// 8-WG group barrier (proven r4/r5). __syncthreads() drains vmcnt before
// s_barrier, so this WG's write-through atomic stores are at the coherent point
// before the arrival add. BOUNDED spin: bugs give wrong answers, never hangs.
__device__ __forceinline__ void gbar(unsigned* cnt, unsigned target) {
  __syncthreads();
  if (threadIdx.x == 0) {
    __hip_atomic_fetch_add(cnt, 1u, __ATOMIC_RELAXED, __HIP_MEMORY_SCOPE_AGENT);
    int i = 0;
    while (__hip_atomic_load(cnt, __ATOMIC_RELAXED, __HIP_MEMORY_SCOPE_AGENT) < target) {
      __builtin_amdgcn_s_sleep(2);
      if (++i >= 30000) break;  // ~ms-scale cap
    }
  }
  __syncthreads();
  __builtin_amdgcn_sched_barrier(0);
}

// Stage the group's 32 rows x 512 cols packed-h tile -> LDS hi/lo planes.
__device__ __forceinline__ void stage_h32(char* sm, const unsigned* hsrc, int row0, int tid) {
  const int cp = tid & 255;
  const int rh = (tid >> 8) << 4;
  const unsigned long long* src =
      (const unsigned long long*)hsrc + ((size_t)(row0 + rh) << 8) + cp;
  unsigned long long b[16];
#pragma unroll
  for (int j = 0; j < 16; ++j) b[j] = ald64(src + (size_t)j * 256);
#pragma unroll
  for (int j = 0; j < 16; ++j) {
    const int row = rh + j;
    const unsigned p0 = (unsigned)b[j];          // col 2cp   : hi | lo<<16
    const unsigned p1 = (unsigned)(b[j] >> 32);  // col 2cp+1
    const unsigned hw = (p0 & 0xffffu) | (p1 << 16);
    const unsigned lw = (p0 >> 16) | (p1 & 0xffff0000u);
    const int sa = SWZ(row, cp << 2);
    *(unsigned*)(sm + sa) = hw;
    *(unsigned*)(sm + LDS_LO + sa) = lw;
  }
}

// gates GEMM: wave computes one 16x16 frag per gate, K=512, bf16 hi/lo 3-pass.
__device__ __forceinline__ void gh3(const char* sm, int rl, int kbb,
                                    const __bf16* __restrict__ Bh,
                                    const __bf16* __restrict__ Bl,
                                    const int (&boff)[3], f32x4 (&acc)[3]) {
#pragma unroll 4
  for (int kc = 0; kc < 16; ++kc) {
    const int sa = SWZ(rl, (kc << 6) + kbb);
    bf16x8 ah = *(const bf16x8*)(sm + sa);
    bf16x8 al = *(const bf16x8*)(sm + LDS_LO + sa);
    const int ko = kc << 5;
#pragma unroll
    for (int f = 0; f < 3; ++f) {
      bf16x8 bh = *(const bf16x8*)(Bh + boff[f] + ko);
      bf16x8 bl = *(const bf16x8*)(Bl + boff[f] + ko);
      acc[f] = mfma16(ah, bh, acc[f]);
      acc[f] = mfma16(al, bh, acc[f]);
      acc[f] = mfma16(ah, bl, acc[f]);
    }
  }
}

__device__ __forceinline__ void gh1(const char* sm, int rl, int kbb,
                                    const __bf16* __restrict__ Bh,
                                    const __bf16* __restrict__ Bl, int boff, f32x4& acc) {
#pragma unroll 4
  for (int kc = 0; kc < 16; ++kc) {
    const int sa = SWZ(rl, (kc << 6) + kbb);
    bf16x8 ah = *(const bf16x8*)(sm + sa);
    bf16x8 al = *(const bf16x8*)(sm + LDS_LO + sa);
    const int ko = kc << 5;
    bf16x8 bh = *(const bf16x8*)(Bh + boff + ko);
    bf16x8 bl = *(const bf16x8*)(Bl + boff + ko);
    acc = mfma16(ah, bh, acc);
    acc = mfma16(al, bh, acc);
    acc = mfma16(ah, bl, acc);
  }
}

__global__ void __launch_bounds__(NTHR, 2) seq2seq_main(
    const float* __restrict__ src, const float* __restrict__ enc_wih,
    const float* __restrict__ enc_bih, const float* __restrict__ enc_bhh,
    const float* __restrict__ dec_wih, const float* __restrict__ dec_bih,
    const float* __restrict__ dec_bhh, const float* __restrict__ b1,
    const float* __restrict__ w2, const float* __restrict__ b2,
    const int* __restrict__ hor, float* __restrict__ out, char* __restrict__ ws) {
  __shared__ f32x4 smv[4096];  // 65536 B exactly
  char* sm = (char*)smv;
  float* yb = (float*)sm;      // aliased
  int* s_pair = (int*)sm;      // aliased (startup only)

  const __bf16* ench_hi = (const __bf16*)(ws + OFF_ENH);
  const __bf16* ench_lo = (const __bf16*)(ws + OFF_ENL);
  const __bf16* dech_hi = (const __bf16*)(ws + OFF_DEH);
  const __bf16* dech_lo = (const __bf16*)(ws + OFF_DEL);
  const __bf16* w1h = (const __bf16*)(ws + OFF_W1H);
  const __bf16* w1l = (const __bf16*)(ws + OFF_W1L);
  unsigned* hp0 = (unsigned*)(ws + OFF_HP0);
  unsigned* hp1 = (unsigned*)(ws + OFF_HP1);
  float* fc1 = (float*)(ws + OFF_FC1);
  unsigned* xcd_cnt = (unsigned*)(ws + OFF_ASN);           // 8 counters, 64B stride
  unsigned* root = (unsigned*)(ws + OFF_ASN + 512);
  unsigned* taken = (unsigned*)(ws + OFF_ASN + 1024);      // 256 pair-claim flags

  const int bid = blockIdx.x;
  const int tid = threadIdx.x;

  // ---- dynamic (G, ct) assignment: column-slice ct == this WG's REAL XCD ----
  // so each XCD's L2 only ever holds its own 1/8 weight slice (L2-residency).
  // Hole-filling CAS pass keeps it correct under ANY (unbalanced) placement.
  if (tid == 0) {
    int xcd;
    asm volatile("s_getreg_b32 %0, hwreg(HW_REG_XCC_ID)" : "=s"(xcd));
    xcd &= 7;
    const unsigned slot = __hip_atomic_fetch_add(&xcd_cnt[xcd * 16], 1u, __ATOMIC_RELAXED,
                                                 __HIP_MEMORY_SCOPE_AGENT);
    int p = -1;
    if (slot < 32u) {
      p = xcd * 32 + (int)slot;
      __hip_atomic_store(&taken[p], 1u, __ATOMIC_RELAXED, __HIP_MEMORY_SCOPE_AGENT);
    }
    __hip_atomic_fetch_add(root, 1u, __ATOMIC_RELEASE, __HIP_MEMORY_SCOPE_AGENT);
    int i = 0;
    while (__hip_atomic_load(root, __ATOMIC_ACQUIRE, __HIP_MEMORY_SCOPE_AGENT) < NWG) {
      __builtin_amdgcn_s_sleep(2);
      if (++i >= 30000) break;
    }
    if (p < 0) {  // claim an unfilled pair
      for (int k = 0; k < 256; ++k) {
        const int j = (bid + k) & 255;
        if (__hip_atomic_load(&taken[j], __ATOMIC_RELAXED, __HIP_MEMORY_SCOPE_AGENT) == 0u) {
          unsigned exp = 0u;
          if (__hip_atomic_compare_exchange_strong(&taken[j], &exp, 1u, __ATOMIC_ACQ_REL,
                                                   __ATOMIC_RELAXED,
                                                   __HIP_MEMORY_SCOPE_AGENT)) {
            p = j;
            break;
          }
        }
      }
    }
    if (p < 0) p = ((bid & 7) << 5) | (bid >> 3);  // defensive; should not trigger
    *s_pair = p;
  }
  __syncthreads();
  const int pr = *s_pair;
  __syncthreads();
  const int ct = pr >> 5;  // 0..7  == this WG's XCD
  const int G = pr & 31;   // 0..31 group = 32-row batch tile

  const int wv = tid >> 6;
  const int lane = tid & 63;
  const int lan15 = lane & 15;
  const int crow = (lane >> 4) << 2;  // C-layout row group
  const int kbe = (lane >> 4) << 3;   // element k-offset in fragment
  const int kbb = kbe << 1;           // byte k-offset
  const int wr = wv & 1;              // row-frag (16 rows)
  const int wc = wv >> 1;             // col-frag (16 cols) within 64-col slice
  const int rl = (wr << 4) + lan15;   // LDS A-row for this lane
  const int row0 = G << 5;
  const int cg = (ct << 6) + (wc << 4) + lan15;  // this lane's hidden column

  unsigned* cnt = (unsigned*)(ws + OFF_BAR) + (G << 5);  // 128B stride per group

  int boff[3];
#pragma unroll
  for (int g = 0; g < 3; ++g) boff[g] = ((g << 9) + cg) * HID + kbe;
  const int boff_fc = cg * HID + kbe;

  // hoisted per-lane encoder gate params (input matmul K=3 inline, f32)
  float wE[3][3], biE[3], bhE[3];
#pragma unroll
  for (int g = 0; g < 3; ++g) {
    const int j = (g << 9) + cg;
    wE[g][0] = enc_wih[j * 3 + 0];
    wE[g][1] = enc_wih[j * 3 + 1];
    wE[g][2] = enc_wih[j * 3 + 2];
    biE[g] = enc_bih[j];
    bhE[g] = enc_bhh[j];
  }

  const f32x4 zf = {0.0f, 0.0f, 0.0f, 0.0f};
  float hpv[4] = {0.f, 0.f, 0.f, 0.f};

  // ================= encoder: 512 steps =================
  for (int t = 0; t < SEQL; ++t) {
    // prefetch x(t) early — independent of h, overlaps the stage latency
    float xv[4][3];
#pragma unroll
    for (int reg = 0; reg < 4; ++reg) {
      const int row = row0 + (wr << 4) + crow + reg;
      const float* xp = src + ((size_t)t * BATCH + row) * 3;
      xv[reg][0] = xp[0];
      xv[reg][1] = xp[1];
      xv[reg][2] = xp[2];
    }

    f32x4 acc[3];
#pragma unroll
    for (int f = 0; f < 3; ++f) acc[f] = zf;

    if (t != 0) {
      stage_h32(sm, (t & 1) ? hp1 : hp0, row0, tid);  // h_t lives in plane t&1
      __syncthreads();
      gh3(sm, rl, kbb, ench_hi, ench_lo, boff, acc);
    }

    unsigned* hn = ((t + 1) & 1) ? hp1 : hp0;
#pragma unroll
    for (int reg = 0; reg < 4; ++reg) {
      const int row = row0 + (wr << 4) + crow + reg;
      const float x0 = xv[reg][0], x1 = xv[reg][1], x2 = xv[reg][2];
      const float gir = fmaf(x0, wE[0][0], fmaf(x1, wE[0][1], fmaf(x2, wE[0][2], biE[0])));
      const float giz = fmaf(x0, wE[1][0], fmaf(x1, wE[1][1], fmaf(x2, wE[1][2], biE[1])));
      const float gin = fmaf(x0, wE[2][0], fmaf(x1, wE[2][1], fmaf(x2, wE[2][2], biE[2])));
      const float rg = sig_(gir + acc[0][reg] + bhE[0]);
      const float zg = sig_(giz + acc[1][reg] + bhE[1]);
      const float ng = tanh_(gin + rg * (acc[2][reg] + bhE[2]));
      const float hv = fmaf(zg, hpv[reg] - ng, ng);  // (1-z)*n + z*h
      hpv[reg] = hv;
      const __bf16 hb = (__bf16)hv;
      const __bf16 lb = (__bf16)(hv - (float)hb);
      const unsigned pw = (unsigned)__builtin_bit_cast(unsigned short, hb) |
                          ((unsigned)__builtin_bit_cast(unsigned short, lb) << 16);
      ast32(hn + (size_t)row * HID + cg, pw);
    }
    gbar(cnt, 8u * (unsigned)(t + 1));
  }

  // ================= decoder =================
  float wD[3], biD[3], bhD[3];
#pragma unroll
  for (int g = 0; g < 3; ++g) {
    const int j = (g << 9) + cg;
    wD[g] = dec_wih[j];
    biD[g] = dec_bih[j];
    bhD[g] = dec_bhh[j];
  }
  const float b1c = b1[cg];
  const float b2v = b2[0];
  float w2p0[4], w2p1[4];
#pragma unroll
  for (int j = 0; j < 4; ++j) {
    w2p0[j] = w2[2 * (lane + j * 64)];
    w2p1[j] = w2[2 * (lane + j * 64) + 1];
  }
  int H = hor[0];
  if (H < 1 || H > 96) H = 96;

  for (int t = 0; t < H; ++t) {
    // ---- phase 1: y(t-1) + GRU gates ----
    float din[4];
    if (t == 0) {
#pragma unroll
      for (int reg = 0; reg < 4; ++reg) {
        const int row = row0 + (wr << 4) + crow + reg;
        din[reg] = src[((size_t)(SEQL - 1) * BATCH + row) * 3];
      }
    } else {
      // each wave reduces 4 rows of fc1 against w2 (y = fc1 @ w2^T + b2)
#pragma unroll
      for (int rr = 0; rr < 4; ++rr) {
        const int row = row0 + (wv << 2) + rr;
        const unsigned long long* fp = (const unsigned long long*)fc1 + ((size_t)row << 8);
        float s = 0.0f;
#pragma unroll
        for (int j = 0; j < 4; ++j) {
          const unsigned long long w = ald64(fp + lane + (j << 6));
          const float f0 = __builtin_bit_cast(float, (unsigned)(w & 0xffffffffULL));
          const float f1 = __builtin_bit_cast(float, (unsigned)(w >> 32));
          s = fmaf(f0, w2p0[j], fmaf(f1, w2p1[j], s));
        }
#pragma unroll
        for (int off = 1; off < 64; off <<= 1) s += __shfl_xor(s, off, 64);
        if (lane == 0) yb[(wv << 2) + rr] = s + b2v;
      }
      __syncthreads();
      if (ct == 0 && tid < 32) out[(size_t)(t - 1) * BATCH + row0 + tid] = yb[tid];
#pragma unroll
      for (int reg = 0; reg < 4; ++reg) din[reg] = yb[(wr << 4) + crow + reg];
      __syncthreads();  // yb dead before stage_h32 overwrites sm[0..]
    }

    {
      stage_h32(sm, (t & 1) ? hp1 : hp0, row0, tid);  // dec h_t in plane t&1
      __syncthreads();
      f32x4 acc[3];
#pragma unroll
      for (int f = 0; f < 3; ++f) acc[f] = zf;
      gh3(sm, rl, kbb, dech_hi, dech_lo, boff, acc);

      unsigned* hn = ((t + 1) & 1) ? hp1 : hp0;
#pragma unroll
      for (int reg = 0; reg < 4; ++reg) {
        const int row = row0 + (wr << 4) + crow + reg;
        const float d = din[reg];
        const float rg = sig_(fmaf(d, wD[0], biD[0]) + acc[0][reg] + bhD[0]);
        const float zg = sig_(fmaf(d, wD[1], biD[1]) + acc[1][reg] + bhD[1]);
        const float ng = tanh_(fmaf(d, wD[2], biD[2]) + rg * (acc[2][reg] + bhD[2]));
        const float hv = fmaf(zg, hpv[reg] - ng, ng);
        hpv[reg] = hv;
        const __bf16 hb = (__bf16)hv;
        const __bf16 lb = (__bf16)(hv - (float)hb);
        const unsigned pw = (unsigned)__builtin_bit_cast(unsigned short, hb) |
                            ((unsigned)__builtin_bit_cast(unsigned short, lb) << 16);
        ast32(hn + (size_t)row * HID + cg, pw);
      }
    }
    gbar(cnt, 8u * (unsigned)(SEQL + 2 * t + 1));

    // ---- phase 2: fc1 = relu(h @ w1^T + b1) ----
    {
      stage_h32(sm, ((t + 1) & 1) ? hp1 : hp0, row0, tid);
      __syncthreads();
      f32x4 fa = zf;
      gh1(sm, rl, kbb, w1h, w1l, boff_fc, fa);
#pragma unroll
      for (int reg = 0; reg < 4; ++reg) {
        const int row = row0 + (wr << 4) + crow + reg;
        astf(&fc1[(size_t)row * HID + cg], fmaxf(fa[reg] + b1c, 0.0f));
      }
    }
    gbar(cnt, 8u * (unsigned)(SEQL + 2 * t + 2));
  }

  // ---- final y for t = H-1 ----
  if (ct == 0) {
#pragma unroll
    for (int rr = 0; rr < 4; ++rr) {
      const int row = row0 + (wv << 2) + rr;
      const unsigned long long* fp = (const unsigned long long*)fc1 + ((size_t)row << 8);
      float s = 0.0f;
#pragma unroll
      for (int j = 0; j < 4; ++j) {
        const unsigned long long w = ald64(fp + lane + (j << 6));
        const float f0 = __builtin_bit_cast(float, (unsigned)(w & 0xffffffffULL));
        const float f1 = __builtin_bit_cast(float, (unsigned)(w >> 32));
        s = fmaf(f0, w2p0[j], fmaf(f1, w2p1[j], s));
      }
#pragma unroll
      for (int off = 1; off < 64; off <<= 1) s += __shfl_xor(s, off, 64);
      if (lane == 0) yb[(wv << 2) + rr] = s + b2v;
    }
    __syncthreads();
    if (tid < 32) out[(size_t)(H - 1) * BATCH + row0 + tid] = yb[tid];
  }
}

extern "C" void kernel_launch(void* const* d_in, const int* in_sizes, int n_in,
                              void* d_out, int out_size, void* d_ws, size_t ws_size,
                              hipStream_t stream) {
  if (ws_size < WS_NEED) return;

  const float* src = (const float*)d_in[0];
  const float* enc_wih = (const float*)d_in[1];
  const float* enc_whh = (const float*)d_in[2];
  const float* enc_bih = (const float*)d_in[3];
  const float* enc_bhh = (const float*)d_in[4];
  const float* dec_wih = (const float*)d_in[5];
  const float* dec_whh = (const float*)d_in[6];
  const float* dec_bih = (const float*)d_in[7];
  const float* dec_bhh = (const float*)d_in[8];
  const float* w1 = (const float*)d_in[9];
  const float* b1 = (const float*)d_in[10];
  const float* w2 = (const float*)d_in[11];
  const float* b2 = (const float*)d_in[12];
  const int* hor = (const int*)d_in[13];
  float* out = (float*)d_out;
  char* ws = (char*)d_ws;

  hipMemsetAsync(ws + OFF_BAR, 0, 8192, stream);  // zero barrier + assignment areas

  split_w<<<dim3(3072), dim3(256), 0, stream>>>(enc_whh, (__bf16*)(ws + OFF_ENH),
                                                (__bf16*)(ws + OFF_ENL), 786432);
  split_w<<<dim3(3072), dim3(256), 0, stream>>>(dec_whh, (__bf16*)(ws + OFF_DEH),
                                                (__bf16*)(ws + OFF_DEL), 786432);
  split_w<<<dim3(1024), dim3(256), 0, stream>>>(w1, (__bf16*)(ws + OFF_W1H),
                                                (__bf16*)(ws + OFF_W1L), 262144);

  void* args[] = {&src, &enc_wih, &enc_bih, &enc_bhh, &dec_wih, &dec_bih, &dec_bhh,
                  &b1, &w2, &b2, &hor, &out, &ws};
  hipLaunchCooperativeKernel((void*)seq2seq_main, dim3(NWG), dim3(NTHR), args, 0, stream);
}

// Round 8
// 15325.244 us; speedup vs baseline: 2.4245x; 1.0453x over previous
//
#include <hip/hip_runtime.h>

typedef __bf16 bf16x8 __attribute__((ext_vector_type(8)));
typedef float f32x4 __attribute__((ext_vector_type(4)));

#define HID 512
#define BATCH 1024
#define SEQL 512
#define NWG 512
#define NTHR 256

// ---- workspace layout (byte offsets) ----
#define OFF_ENH 0u          // enc_whh hi : 1536*512*2
#define OFF_ENL 1572864u
#define OFF_DEH 3145728u
#define OFF_DEL 4718592u
#define OFF_W1H 6291456u    // w1 hi : 512*512*2
#define OFF_W1L 6815744u
#define OFF_HP0 7340032u    // packed h (bf16 hi | lo<<16) u32 [1024][512] = 2MB
#define OFF_HP1 9437184u
#define OFF_FC1 11534336u   // fc1 f32 : 2MB
#define OFF_BAR 13631488u   // 64 group counters, 128B stride = 8KB (zeroed each call)
#define WS_NEED 13639680u

// LDS = 32KB: A-tile hi plane [16][512]bf16 (16KB) at 0, lo at 16384.
// yb (64B) aliases sm[0..63]; uses sync-separated from the planes.
#define LDS_LO 16384
#define SWZ(row, cb) (((row) << 10) + ((cb) ^ (((row) & 7) << 4)))

__device__ __forceinline__ f32x4 mfma16(bf16x8 a, bf16x8 b, f32x4 c) {
  return __builtin_amdgcn_mfma_f32_16x16x32_bf16(a, b, c, 0, 0, 0);
}
__device__ __forceinline__ float sig_(float x) { return 1.0f / (1.0f + __expf(-x)); }
__device__ __forceinline__ float tanh_(float x) { return 1.0f - 2.0f / (__expf(2.0f * x) + 1.0f); }

// Agent-scope relaxed atomics: served at the coherent point; correct regardless
// of WG->XCD placement; never invalidates caches.
__device__ __forceinline__ unsigned long long ald64(const void* p) {
  return __hip_atomic_load((const unsigned long long*)p, __ATOMIC_RELAXED,
                           __HIP_MEMORY_SCOPE_AGENT);
}
__device__ __forceinline__ void ast32(void* p, unsigned v) {
  __hip_atomic_store((unsigned*)p, v, __ATOMIC_RELAXED, __HIP_MEMORY_SCOPE_AGENT);
}
__device__ __forceinline__ void astf(void* p, float v) {
  __hip_atomic_store((float*)p, v, __ATOMIC_RELAXED, __HIP_MEMORY_SCOPE_AGENT);
}

__global__ void split_w(const float* __restrict__ a, __bf16* __restrict__ hi,
                        __bf16* __restrict__ lo, int n) {
  int i = blockIdx.x * blockDim.x + threadIdx.x;
  if (i < n) {
    float v = a[i];
    __bf16 h = (__bf16)v;
    hi[i] = h;
    lo[i] = (__bf16)(v - (float)h);
  }
}

// 8-WG group barrier (proven r4-r6). __syncthreads() drains vmcnt before
// s_barrier, so this WG's write-through atomic stores are at the coherent point
// before the arrival add. BOUNDED spin: bugs give wrong answers, never hangs.
__device__ __forceinline__ void gbar(unsigned* cnt, unsigned target) {
  __syncthreads();
  if (threadIdx.x == 0) {
    __hip_atomic_fetch_add(cnt, 1u, __ATOMIC_RELAXED, __HIP_MEMORY_SCOPE_AGENT);
    int i = 0;
    while (__hip_atomic_load(cnt, __ATOMIC_RELAXED, __HIP_MEMORY_SCOPE_AGENT) < target) {
      __builtin_amdgcn_s_sleep(2);
      if (++i >= 30000) break;  // ~ms-scale cap
    }
  }
  __syncthreads();
  __builtin_amdgcn_sched_barrier(0);
}

// Stage the group's 16 rows x 512 cols packed-h tile -> LDS hi/lo planes.
// Thread tid owns u64 col-pair tid (u32 cols 2t,2t+1) for all 16 rows.
__device__ __forceinline__ void stage_h16(char* sm, const unsigned* hsrc, int row0, int tid) {
  const unsigned long long* src = (const unsigned long long*)hsrc + ((size_t)row0 << 8) + tid;
  unsigned long long b[16];
#pragma unroll
  for (int j = 0; j < 16; ++j) b[j] = ald64(src + (size_t)j * 256);
#pragma unroll
  for (int j = 0; j < 16; ++j) {
    const unsigned p0 = (unsigned)b[j];          // col 2t   : hi | lo<<16
    const unsigned p1 = (unsigned)(b[j] >> 32);  // col 2t+1
    const unsigned hw = (p0 & 0xffffu) | (p1 << 16);
    const unsigned lw = (p0 >> 16) | (p1 & 0xffff0000u);
    const int sa = SWZ(j, tid << 2);
    *(unsigned*)(sm + sa) = hw;
    *(unsigned*)(sm + LDS_LO + sa) = lw;
  }
}

// gates GEMM: wave computes one 16x16 frag per gate, K=512, bf16 hi/lo 3-pass.
// A from LDS, B (weights) from global (L2-hot).
__device__ __forceinline__ void gh3(const char* sm, int rl, int kbb,
                                    const __bf16* __restrict__ Bh,
                                    const __bf16* __restrict__ Bl,
                                    const int (&boff)[3], f32x4 (&acc)[3]) {
#pragma unroll 4
  for (int kc = 0; kc < 16; ++kc) {
    const int sa = SWZ(rl, (kc << 6) + kbb);
    bf16x8 ah = *(const bf16x8*)(sm + sa);
    bf16x8 al = *(const bf16x8*)(sm + LDS_LO + sa);
    const int ko = kc << 5;
#pragma unroll
    for (int f = 0; f < 3; ++f) {
      bf16x8 bh = *(const bf16x8*)(Bh + boff[f] + ko);
      bf16x8 bl = *(const bf16x8*)(Bl + boff[f] + ko);
      acc[f] = mfma16(ah, bh, acc[f]);
      acc[f] = mfma16(al, bh, acc[f]);
      acc[f] = mfma16(ah, bl, acc[f]);
    }
  }
}

__device__ __forceinline__ void gh1(const char* sm, int rl, int kbb,
                                    const __bf16* __restrict__ Bh,
                                    const __bf16* __restrict__ Bl, int boff, f32x4& acc) {
#pragma unroll 4
  for (int kc = 0; kc < 16; ++kc) {
    const int sa = SWZ(rl, (kc << 6) + kbb);
    bf16x8 ah = *(const bf16x8*)(sm + sa);
    bf16x8 al = *(const bf16x8*)(sm + LDS_LO + sa);
    const int ko = kc << 5;
    bf16x8 bh = *(const bf16x8*)(Bh + boff + ko);
    bf16x8 bl = *(const bf16x8*)(Bl + boff + ko);
    acc = mfma16(ah, bh, acc);
    acc = mfma16(al, bh, acc);
    acc = mfma16(ah, bl, acc);
  }
}

__global__ void __launch_bounds__(NTHR, 4) seq2seq_main(
    const float* __restrict__ src, const float* __restrict__ enc_wih,
    const float* __restrict__ enc_bih, const float* __restrict__ enc_bhh,
    const float* __restrict__ dec_wih, const float* __restrict__ dec_bih,
    const float* __restrict__ dec_bhh, const float* __restrict__ b1,
    const float* __restrict__ w2, const float* __restrict__ b2,
    const int* __restrict__ hor, float* __restrict__ out, char* __restrict__ ws) {
  __shared__ f32x4 smv[2048];  // 32768 B
  char* sm = (char*)smv;
  float* yb = (float*)sm;  // aliased (sync-separated)

  const __bf16* ench_hi = (const __bf16*)(ws + OFF_ENH);
  const __bf16* ench_lo = (const __bf16*)(ws + OFF_ENL);
  const __bf16* dech_hi = (const __bf16*)(ws + OFF_DEH);
  const __bf16* dech_lo = (const __bf16*)(ws + OFF_DEL);
  const __bf16* w1h = (const __bf16*)(ws + OFF_W1H);
  const __bf16* w1l = (const __bf16*)(ws + OFF_W1L);
  unsigned* hp0 = (unsigned*)(ws + OFF_HP0);
  unsigned* hp1 = (unsigned*)(ws + OFF_HP1);
  float* fc1 = (float*)(ws + OFF_FC1);

  // group G (=bid>>3) owns batch rows [16G, 16G+16); member ct (=bid&7) owns a
  // 64-col slice. Groups are independent pipelines; grid 512 = 2 WGs/CU, and
  // bids b, b+256 (different groups) share a CU -> mutual stall hiding.
  // Plain launch: grid == exact co-residency capacity (LDS 32KB -> 5/CU,
  // VGPR<=128 -> 4 waves/SIMD, threads -> 8/CU; binding = 512/256CU = 2/CU).
  const int bid = blockIdx.x;
  const int G = bid >> 3;
  const int ct = bid & 7;
  const int tid = threadIdx.x;
  const int wv = tid >> 6;
  const int lane = tid & 63;
  const int lan15 = lane & 15;
  const int crow = (lane >> 4) << 2;  // C-layout row group
  const int kbe = (lane >> 4) << 3;   // element k-offset in fragment
  const int kbb = kbe << 1;           // byte k-offset
  const int rl = lan15;               // LDS A-row for this lane
  const int row0 = G << 4;
  const int cg = (ct << 6) + (wv << 4) + lan15;  // this lane's hidden column

  unsigned* cnt = (unsigned*)(ws + OFF_BAR) + (G << 5);  // 128B stride per group

  int boff[3];
#pragma unroll
  for (int g = 0; g < 3; ++g) boff[g] = ((g << 9) + cg) * HID + kbe;
  const int boff_fc = cg * HID + kbe;

  // hoisted per-lane encoder gate params (input matmul K=3 inline, f32)
  float wE[3][3], biE[3], bhE[3];
#pragma unroll
  for (int g = 0; g < 3; ++g) {
    const int j = (g << 9) + cg;
    wE[g][0] = enc_wih[j * 3 + 0];
    wE[g][1] = enc_wih[j * 3 + 1];
    wE[g][2] = enc_wih[j * 3 + 2];
    biE[g] = enc_bih[j];
    bhE[g] = enc_bhh[j];
  }

  const f32x4 zf = {0.0f, 0.0f, 0.0f, 0.0f};
  float hpv[4] = {0.f, 0.f, 0.f, 0.f};

  // ================= encoder: 512 steps =================
  for (int t = 0; t < SEQL; ++t) {
    // prefetch x(t) early; independent of h, overlaps the stage latency
    float xv[4][3];
#pragma unroll
    for (int reg = 0; reg < 4; ++reg) {
      const int row = row0 + crow + reg;
      const float* xp = src + ((size_t)t * BATCH + row) * 3;
      xv[reg][0] = xp[0];
      xv[reg][1] = xp[1];
      xv[reg][2] = xp[2];
    }

    f32x4 acc[3];
#pragma unroll
    for (int f = 0; f < 3; ++f) acc[f] = zf;

    if (t != 0) {
      stage_h16(sm, (t & 1) ? hp1 : hp0, row0, tid);  // h_t lives in plane t&1
      __syncthreads();
      gh3(sm, rl, kbb, ench_hi, ench_lo, boff, acc);
    }

    unsigned* hn = ((t + 1) & 1) ? hp1 : hp0;
#pragma unroll
    for (int reg = 0; reg < 4; ++reg) {
      const int row = row0 + crow + reg;
      const float x0 = xv[reg][0], x1 = xv[reg][1], x2 = xv[reg][2];
      const float gir = fmaf(x0, wE[0][0], fmaf(x1, wE[0][1], fmaf(x2, wE[0][2], biE[0])));
      const float giz = fmaf(x0, wE[1][0], fmaf(x1, wE[1][1], fmaf(x2, wE[1][2], biE[1])));
      const float gin = fmaf(x0, wE[2][0], fmaf(x1, wE[2][1], fmaf(x2, wE[2][2], biE[2])));
      const float rg = sig_(gir + acc[0][reg] + bhE[0]);
      const float zg = sig_(giz + acc[1][reg] + bhE[1]);
      const float ng = tanh_(gin + rg * (acc[2][reg] + bhE[2]));
      const float hv = fmaf(zg, hpv[reg] - ng, ng);  // (1-z)*n + z*h
      hpv[reg] = hv;
      const __bf16 hb = (__bf16)hv;
      const __bf16 lb = (__bf16)(hv - (float)hb);
      const unsigned pw = (unsigned)__builtin_bit_cast(unsigned short, hb) |
                          ((unsigned)__builtin_bit_cast(unsigned short, lb) << 16);
      ast32(hn + (size_t)row * HID + cg, pw);
    }
    gbar(cnt, 8u * (unsigned)(t + 1));
  }

  // ================= decoder =================
  float wD[3], biD[3], bhD[3];
#pragma unroll
  for (int g = 0; g < 3; ++g) {
    const int j = (g << 9) + cg;
    wD[g] = dec_wih[j];
    biD[g] = dec_bih[j];
    bhD[g] = dec_bhh[j];
  }
  const float b1c = b1[cg];
  const float b2v = b2[0];
  float w2p0[4], w2p1[4];
#pragma unroll
  for (int j = 0; j < 4; ++j) {
    w2p0[j] = w2[2 * (lane + j * 64)];
    w2p1[j] = w2[2 * (lane + j * 64) + 1];
  }
  int H = hor[0];
  if (H < 1 || H > 96) H = 96;

  for (int t = 0; t < H; ++t) {
    // ---- phase 1: y(t-1) + GRU gates ----
    float din[4];
    if (t == 0) {
#pragma unroll
      for (int reg = 0; reg < 4; ++reg) {
        const int row = row0 + crow + reg;
        din[reg] = src[((size_t)(SEQL - 1) * BATCH + row) * 3];
      }
    } else {
      // each wave reduces 4 rows of fc1 against w2 (y = fc1 @ w2^T + b2)
#pragma unroll
      for (int rr = 0; rr < 4; ++rr) {
        const int row = row0 + (wv << 2) + rr;
        const unsigned long long* fp = (const unsigned long long*)fc1 + ((size_t)row << 8);
        float s = 0.0f;
#pragma unroll
        for (int j = 0; j < 4; ++j) {
          const unsigned long long w = ald64(fp + lane + (j << 6));
          const float f0 = __builtin_bit_cast(float, (unsigned)(w & 0xffffffffULL));
          const float f1 = __builtin_bit_cast(float, (unsigned)(w >> 32));
          s = fmaf(f0, w2p0[j], fmaf(f1, w2p1[j], s));
        }
#pragma unroll
        for (int off = 1; off < 64; off <<= 1) s += __shfl_xor(s, off, 64);
        if (lane == 0) yb[(wv << 2) + rr] = s + b2v;
      }
      __syncthreads();
      if (ct == 0 && tid < 16) out[(size_t)(t - 1) * BATCH + row0 + tid] = yb[tid];
#pragma unroll
      for (int reg = 0; reg < 4; ++reg) din[reg] = yb[crow + reg];
      __syncthreads();  // yb dead before stage overwrites sm[0..]
    }

    {
      stage_h16(sm, (t & 1) ? hp1 : hp0, row0, tid);  // dec h_t in plane t&1
      __syncthreads();
      f32x4 acc[3];
#pragma unroll
      for (int f = 0; f < 3; ++f) acc[f] = zf;
      gh3(sm, rl, kbb, dech_hi, dech_lo, boff, acc);

      unsigned* hn = ((t + 1) & 1) ? hp1 : hp0;
#pragma unroll
      for (int reg = 0; reg < 4; ++reg) {
        const int row = row0 + crow + reg;
        const float d = din[reg];
        const float rg = sig_(fmaf(d, wD[0], biD[0]) + acc[0][reg] + bhD[0]);
        const float zg = sig_(fmaf(d, wD[1], biD[1]) + acc[1][reg] + bhD[1]);
        const float ng = tanh_(fmaf(d, wD[2], biD[2]) + rg * (acc[2][reg] + bhD[2]));
        const float hv = fmaf(zg, hpv[reg] - ng, ng);
        hpv[reg] = hv;
        const __bf16 hb = (__bf16)hv;
        const __bf16 lb = (__bf16)(hv - (float)hb);
        const unsigned pw = (unsigned)__builtin_bit_cast(unsigned short, hb) |
                            ((unsigned)__builtin_bit_cast(unsigned short, lb) << 16);
        ast32(hn + (size_t)row * HID + cg, pw);
      }
    }
    gbar(cnt, 8u * (unsigned)(SEQL + 2 * t + 1));

    // ---- phase 2: fc1 = relu(h @ w1^T + b1) ----
    {
      stage_h16(sm, ((t + 1) & 1) ? hp1 : hp0, row0, tid);
      __syncthreads();
      f32x4 fa = zf;
      gh1(sm, rl, kbb, w1h, w1l, boff_fc, fa);
#pragma unroll
      for (int reg = 0; reg < 4; ++reg) {
        const int row = row0 + crow + reg;
        astf(&fc1[(size_t)row * HID + cg], fmaxf(fa[reg] + b1c, 0.0f));
      }
    }
    gbar(cnt, 8u * (unsigned)(SEQL + 2 * t + 2));
  }

  // ---- final y for t = H-1 ----
  if (ct == 0) {
#pragma unroll
    for (int rr = 0; rr < 4; ++rr) {
      const int row = row0 + (wv << 2) + rr;
      const unsigned long long* fp = (const unsigned long long*)fc1 + ((size_t)row << 8);
      float s = 0.0f;
#pragma unroll
      for (int j = 0; j < 4; ++j) {
        const unsigned long long w = ald64(fp + lane + (j << 6));
        const float f0 = __builtin_bit_cast(float, (unsigned)(w & 0xffffffffULL));
        const float f1 = __builtin_bit_cast(float, (unsigned)(w >> 32));
        s = fmaf(f0, w2p0[j], fmaf(f1, w2p1[j], s));
      }
#pragma unroll
      for (int off = 1; off < 64; off <<= 1) s += __shfl_xor(s, off, 64);
      if (lane == 0) yb[(wv << 2) + rr] = s + b2v;
    }
    __syncthreads();
    if (tid < 16) out[(size_t)(H - 1) * BATCH + row0 + tid] = yb[tid];
  }
}

extern "C" void kernel_launch(void* const* d_in, const int* in_sizes, int n_in,
                              void* d_out, int out_size, void* d_ws, size_t ws_size,
                              hipStream_t stream) {
  if (ws_size < WS_NEED) return;

  const float* src = (const float*)d_in[0];
  const float* enc_wih = (const float*)d_in[1];
  const float* enc_whh = (const float*)d_in[2];
  const float* enc_bih = (const float*)d_in[3];
  const float* enc_bhh = (const float*)d_in[4];
  const float* dec_wih = (const float*)d_in[5];
  const float* dec_whh = (const float*)d_in[6];
  const float* dec_bih = (const float*)d_in[7];
  const float* dec_bhh = (const float*)d_in[8];
  const float* w1 = (const float*)d_in[9];
  const float* b1 = (const float*)d_in[10];
  const float* w2 = (const float*)d_in[11];
  const float* b2 = (const float*)d_in[12];
  const int* hor = (const int*)d_in[13];
  float* out = (float*)d_out;
  char* ws = (char*)d_ws;

  hipMemsetAsync(ws + OFF_BAR, 0, 8192, stream);  // zero barrier counters every call

  split_w<<<dim3(3072), dim3(256), 0, stream>>>(enc_whh, (__bf16*)(ws + OFF_ENH),
                                                (__bf16*)(ws + OFF_ENL), 786432);
  split_w<<<dim3(3072), dim3(256), 0, stream>>>(dec_whh, (__bf16*)(ws + OFF_DEH),
                                                (__bf16*)(ws + OFF_DEL), 786432);
  split_w<<<dim3(1024), dim3(256), 0, stream>>>(w1, (__bf16*)(ws + OFF_W1H),
                                                (__bf16*)(ws + OFF_W1L), 262144);

  // Plain (non-cooperative) launch: grid sized to exact co-residency capacity;
  // the bounded-spin group barrier needs no cooperative guarantee, and plain
  // launch cannot be silently rejected the way hipLaunchCooperativeKernel was.
  seq2seq_main<<<dim3(NWG), dim3(NTHR), 0, stream>>>(
      src, enc_wih, enc_bih, enc_bhh, dec_wih, dec_bih, dec_bhh, b1, w2, b2, hor, out, ws);
}

// Round 11
// 15209.818 us; speedup vs baseline: 2.4429x; 1.0076x over previous
//
#include <hip/hip_runtime.h>

typedef __bf16 bf16x8 __attribute__((ext_vector_type(8)));
typedef float f32x4 __attribute__((ext_vector_type(4)));

#define HID 512
#define BATCH 1024
#define SEQL 512
#define NWG 512
#define NTHR 256

// ---- workspace layout (byte offsets) ----
#define OFF_ENH 0u          // enc_whh hi : 1536*512*2
#define OFF_ENL 1572864u
#define OFF_DEH 3145728u
#define OFF_DEL 4718592u
#define OFF_W1H 6291456u    // w1 hi : 512*512*2
#define OFF_W1L 6815744u
#define OFF_HP0 7340032u    // packed h (bf16 hi | lo<<16) u32 [1024][512] = 2MB
#define OFF_HP1 9437184u
#define OFF_FC1 11534336u   // fc1 f32 : 2MB
#define OFF_BAR 13631488u   // 64 group counters, 128B stride = 8KB (zeroed each call)
#define WS_NEED 13639680u

// LDS = 32KB: A-tile hi plane [16][512]bf16 (16KB) at 0, lo at 16384.
// yb (64B) aliases sm[0..63]; uses sync-separated from the planes.
#define LDS_LO 16384
#define SWZ(row, cb) (((row) << 10) + ((cb) ^ (((row) & 7) << 4)))

__device__ __forceinline__ f32x4 mfma16(bf16x8 a, bf16x8 b, f32x4 c) {
  return __builtin_amdgcn_mfma_f32_16x16x32_bf16(a, b, c, 0, 0, 0);
}
__device__ __forceinline__ float sig_(float x) { return 1.0f / (1.0f + __expf(-x)); }
__device__ __forceinline__ float tanh_(float x) { return 1.0f - 2.0f / (__expf(2.0f * x) + 1.0f); }

// Agent-scope relaxed atomics: served at the coherent point; correct regardless
// of WG->XCD placement; never invalidates caches. (sc0/L2-local path falsified
// in r9/r10 — do not resurrect.)
__device__ __forceinline__ unsigned long long ald64(const void* p) {
  return __hip_atomic_load((const unsigned long long*)p, __ATOMIC_RELAXED,
                           __HIP_MEMORY_SCOPE_AGENT);
}
__device__ __forceinline__ void ast32(void* p, unsigned v) {
  __hip_atomic_store((unsigned*)p, v, __ATOMIC_RELAXED, __HIP_MEMORY_SCOPE_AGENT);
}
__device__ __forceinline__ void astf(void* p, float v) {
  __hip_atomic_store((float*)p, v, __ATOMIC_RELAXED, __HIP_MEMORY_SCOPE_AGENT);
}

__global__ void split_w(const float* __restrict__ a, __bf16* __restrict__ hi,
                        __bf16* __restrict__ lo, int n) {
  int i = blockIdx.x * blockDim.x + threadIdx.x;
  if (i < n) {
    float v = a[i];
    __bf16 h = (__bf16)v;
    hi[i] = h;
    lo[i] = (__bf16)(v - (float)h);
  }
}

// 8-WG group barrier (proven r4-r8). __syncthreads() drains vmcnt before
// s_barrier, so this WG's write-through atomic stores are at the coherent point
// before the arrival add. BOUNDED spin: bugs give wrong answers, never hangs.
__device__ __forceinline__ void gbar(unsigned* cnt, unsigned target) {
  __syncthreads();
  if (threadIdx.x == 0) {
    __hip_atomic_fetch_add(cnt, 1u, __ATOMIC_RELAXED, __HIP_MEMORY_SCOPE_AGENT);
    int i = 0;
    while (__hip_atomic_load(cnt, __ATOMIC_RELAXED, __HIP_MEMORY_SCOPE_AGENT) < target) {
      __builtin_amdgcn_s_sleep(2);
      if (++i >= 30000) break;  // ~ms-scale cap
    }
  }
  __syncthreads();
  __builtin_amdgcn_sched_barrier(0);
}

// Stage the group's 16 rows x 512 cols packed-h tile -> LDS hi/lo planes.
// Thread tid owns u64 col-pair tid (u32 cols 2t,2t+1) for all 16 rows.
// With the 256-VGPR budget all 16 loads stay in flight (one IC latency total).
__device__ __forceinline__ void stage_h16(char* sm, const unsigned* hsrc, int row0, int tid) {
  const unsigned long long* src = (const unsigned long long*)hsrc + ((size_t)row0 << 8) + tid;
  unsigned long long b[16];
#pragma unroll
  for (int j = 0; j < 16; ++j) b[j] = ald64(src + (size_t)j * 256);
#pragma unroll
  for (int j = 0; j < 16; ++j) {
    const unsigned p0 = (unsigned)b[j];          // col 2t   : hi | lo<<16
    const unsigned p1 = (unsigned)(b[j] >> 32);  // col 2t+1
    const unsigned hw = (p0 & 0xffffu) | (p1 << 16);
    const unsigned lw = (p0 >> 16) | (p1 & 0xffff0000u);
    const int sa = SWZ(j, tid << 2);
    *(unsigned*)(sm + sa) = hw;
    *(unsigned*)(sm + LDS_LO + sa) = lw;
  }
}

// gates GEMM: wave computes one 16x16 frag per gate, K=512, bf16 hi/lo 3-pass.
// A from LDS, B (weights) from global (L2-hot). unroll 8: up to ~48 B-loads in
// the scheduling window so L2 latency is pipelined, not serialized.
__device__ __forceinline__ void gh3(const char* sm, int rl, int kbb,
                                    const __bf16* __restrict__ Bh,
                                    const __bf16* __restrict__ Bl,
                                    const int (&boff)[3], f32x4 (&acc)[3]) {
#pragma unroll 8
  for (int kc = 0; kc < 16; ++kc) {
    const int sa = SWZ(rl, (kc << 6) + kbb);
    bf16x8 ah = *(const bf16x8*)(sm + sa);
    bf16x8 al = *(const bf16x8*)(sm + LDS_LO + sa);
    const int ko = kc << 5;
#pragma unroll
    for (int f = 0; f < 3; ++f) {
      bf16x8 bh = *(const bf16x8*)(Bh + boff[f] + ko);
      bf16x8 bl = *(const bf16x8*)(Bl + boff[f] + ko);
      acc[f] = mfma16(ah, bh, acc[f]);
      acc[f] = mfma16(al, bh, acc[f]);
      acc[f] = mfma16(ah, bl, acc[f]);
    }
  }
}

__device__ __forceinline__ void gh1(const char* sm, int rl, int kbb,
                                    const __bf16* __restrict__ Bh,
                                    const __bf16* __restrict__ Bl, int boff, f32x4& acc) {
#pragma unroll 8
  for (int kc = 0; kc < 16; ++kc) {
    const int sa = SWZ(rl, (kc << 6) + kbb);
    bf16x8 ah = *(const bf16x8*)(sm + sa);
    bf16x8 al = *(const bf16x8*)(sm + LDS_LO + sa);
    const int ko = kc << 5;
    bf16x8 bh = *(const bf16x8*)(Bh + boff + ko);
    bf16x8 bl = *(const bf16x8*)(Bl + boff + ko);
    acc = mfma16(ah, bh, acc);
    acc = mfma16(al, bh, acc);
    acc = mfma16(ah, bl, acc);
  }
}

// launch_bounds(256, 2): grid gives 2 blocks/CU = 8 waves/CU = 2 waves/SIMD
// ALREADY, so a 4-waves/SIMD VGPR cap (<=128, compiler chose 64 in r8) only
// starved memory ILP. 2 waves/SIMD -> 256-VGPR budget at identical occupancy.
__global__ void __launch_bounds__(NTHR, 2) seq2seq_main(
    const float* __restrict__ src, const float* __restrict__ enc_wih,
    const float* __restrict__ enc_bih, const float* __restrict__ enc_bhh,
    const float* __restrict__ dec_wih, const float* __restrict__ dec_bih,
    const float* __restrict__ dec_bhh, const float* __restrict__ b1,
    const float* __restrict__ w2, const float* __restrict__ b2,
    const int* __restrict__ hor, float* __restrict__ out, char* __restrict__ ws) {
  __shared__ f32x4 smv[2048];  // 32768 B
  char* sm = (char*)smv;
  float* yb = (float*)sm;  // aliased (sync-separated)

  const __bf16* ench_hi = (const __bf16*)(ws + OFF_ENH);
  const __bf16* ench_lo = (const __bf16*)(ws + OFF_ENL);
  const __bf16* dech_hi = (const __bf16*)(ws + OFF_DEH);
  const __bf16* dech_lo = (const __bf16*)(ws + OFF_DEL);
  const __bf16* w1h = (const __bf16*)(ws + OFF_W1H);
  const __bf16* w1l = (const __bf16*)(ws + OFF_W1L);
  unsigned* hp0 = (unsigned*)(ws + OFF_HP0);
  unsigned* hp1 = (unsigned*)(ws + OFF_HP1);
  float* fc1 = (float*)(ws + OFF_FC1);

  // group G (=bid>>3) owns batch rows [16G, 16G+16); member ct (=bid&7) owns a
  // 64-col slice. Groups are independent pipelines; 2 co-resident WGs/CU from
  // different groups hide each other's stalls.
  const int bid = blockIdx.x;
  const int G = bid >> 3;
  const int ct = bid & 7;
  const int tid = threadIdx.x;
  const int wv = tid >> 6;
  const int lane = tid & 63;
  const int lan15 = lane & 15;
  const int crow = (lane >> 4) << 2;  // C-layout row group
  const int kbe = (lane >> 4) << 3;   // element k-offset in fragment
  const int kbb = kbe << 1;           // byte k-offset
  const int rl = lan15;               // LDS A-row for this lane
  const int row0 = G << 4;
  const int cg = (ct << 6) + (wv << 4) + lan15;  // this lane's hidden column

  unsigned* cnt = (unsigned*)(ws + OFF_BAR) + (G << 5);  // 128B stride per group

  int boff[3];
#pragma unroll
  for (int g = 0; g < 3; ++g) boff[g] = ((g << 9) + cg) * HID + kbe;
  const int boff_fc = cg * HID + kbe;

  // hoisted per-lane encoder gate params (input matmul K=3 inline, f32)
  float wE[3][3], biE[3], bhE[3];
#pragma unroll
  for (int g = 0; g < 3; ++g) {
    const int j = (g << 9) + cg;
    wE[g][0] = enc_wih[j * 3 + 0];
    wE[g][1] = enc_wih[j * 3 + 1];
    wE[g][2] = enc_wih[j * 3 + 2];
    biE[g] = enc_bih[j];
    bhE[g] = enc_bhh[j];
  }

  const f32x4 zf = {0.0f, 0.0f, 0.0f, 0.0f};
  float hpv[4] = {0.f, 0.f, 0.f, 0.f};

  // ================= encoder: 512 steps =================
  for (int t = 0; t < SEQL; ++t) {
    // prefetch x(t) early; independent of h, overlaps the stage latency
    float xv[4][3];
#pragma unroll
    for (int reg = 0; reg < 4; ++reg) {
      const int row = row0 + crow + reg;
      const float* xp = src + ((size_t)t * BATCH + row) * 3;
      xv[reg][0] = xp[0];
      xv[reg][1] = xp[1];
      xv[reg][2] = xp[2];
    }

    f32x4 acc[3];
#pragma unroll
    for (int f = 0; f < 3; ++f) acc[f] = zf;

    if (t != 0) {
      stage_h16(sm, (t & 1) ? hp1 : hp0, row0, tid);  // h_t lives in plane t&1
      __syncthreads();
      gh3(sm, rl, kbb, ench_hi, ench_lo, boff, acc);
    }

    unsigned* hn = ((t + 1) & 1) ? hp1 : hp0;
#pragma unroll
    for (int reg = 0; reg < 4; ++reg) {
      const int row = row0 + crow + reg;
      const float x0 = xv[reg][0], x1 = xv[reg][1], x2 = xv[reg][2];
      const float gir = fmaf(x0, wE[0][0], fmaf(x1, wE[0][1], fmaf(x2, wE[0][2], biE[0])));
      const float giz = fmaf(x0, wE[1][0], fmaf(x1, wE[1][1], fmaf(x2, wE[1][2], biE[1])));
      const float gin = fmaf(x0, wE[2][0], fmaf(x1, wE[2][1], fmaf(x2, wE[2][2], biE[2])));
      const float rg = sig_(gir + acc[0][reg] + bhE[0]);
      const float zg = sig_(giz + acc[1][reg] + bhE[1]);
      const float ng = tanh_(gin + rg * (acc[2][reg] + bhE[2]));
      const float hv = fmaf(zg, hpv[reg] - ng, ng);  // (1-z)*n + z*h
      hpv[reg] = hv;
      const __bf16 hb = (__bf16)hv;
      const __bf16 lb = (__bf16)(hv - (float)hb);
      const unsigned pw = (unsigned)__builtin_bit_cast(unsigned short, hb) |
                          ((unsigned)__builtin_bit_cast(unsigned short, lb) << 16);
      ast32(hn + (size_t)row * HID + cg, pw);
    }
    gbar(cnt, 8u * (unsigned)(t + 1));
  }

  // ================= decoder =================
  float wD[3], biD[3], bhD[3];
#pragma unroll
  for (int g = 0; g < 3; ++g) {
    const int j = (g << 9) + cg;
    wD[g] = dec_wih[j];
    biD[g] = dec_bih[j];
    bhD[g] = dec_bhh[j];
  }
  const float b1c = b1[cg];
  const float b2v = b2[0];
  float w2p0[4], w2p1[4];
#pragma unroll
  for (int j = 0; j < 4; ++j) {
    w2p0[j] = w2[2 * (lane + j * 64)];
    w2p1[j] = w2[2 * (lane + j * 64) + 1];
  }
  int H = hor[0];
  if (H < 1 || H > 96) H = 96;

  for (int t = 0; t < H; ++t) {
    // ---- phase 1: y(t-1) + GRU gates ----
    float din[4];
    if (t == 0) {
#pragma unroll
      for (int reg = 0; reg < 4; ++reg) {
        const int row = row0 + crow + reg;
        din[reg] = src[((size_t)(SEQL - 1) * BATCH + row) * 3];
      }
    } else {
      // each wave reduces 4 rows of fc1 against w2 (y = fc1 @ w2^T + b2)
#pragma unroll
      for (int rr = 0; rr < 4; ++rr) {
        const int row = row0 + (wv << 2) + rr;
        const unsigned long long* fp = (const unsigned long long*)fc1 + ((size_t)row << 8);
        float s = 0.0f;
#pragma unroll
        for (int j = 0; j < 4; ++j) {
          const unsigned long long w = ald64(fp + lane + (j << 6));
          const float f0 = __builtin_bit_cast(float, (unsigned)(w & 0xffffffffULL));
          const float f1 = __builtin_bit_cast(float, (unsigned)(w >> 32));
          s = fmaf(f0, w2p0[j], fmaf(f1, w2p1[j], s));
        }
#pragma unroll
        for (int off = 1; off < 64; off <<= 1) s += __shfl_xor(s, off, 64);
        if (lane == 0) yb[(wv << 2) + rr] = s + b2v;
      }
      __syncthreads();
      if (ct == 0 && tid < 16) out[(size_t)(t - 1) * BATCH + row0 + tid] = yb[tid];
#pragma unroll
      for (int reg = 0; reg < 4; ++reg) din[reg] = yb[crow + reg];
      __syncthreads();  // yb dead before stage overwrites sm[0..]
    }

    {
      stage_h16(sm, (t & 1) ? hp1 : hp0, row0, tid);  // dec h_t in plane t&1
      __syncthreads();
      f32x4 acc[3];
#pragma unroll
      for (int f = 0; f < 3; ++f) acc[f] = zf;
      gh3(sm, rl, kbb, dech_hi, dech_lo, boff, acc);

      unsigned* hn = ((t + 1) & 1) ? hp1 : hp0;
#pragma unroll
      for (int reg = 0; reg < 4; ++reg) {
        const int row = row0 + crow + reg;
        const float d = din[reg];
        const float rg = sig_(fmaf(d, wD[0], biD[0]) + acc[0][reg] + bhD[0]);
        const float zg = sig_(fmaf(d, wD[1], biD[1]) + acc[1][reg] + bhD[1]);
        const float ng = tanh_(fmaf(d, wD[2], biD[2]) + rg * (acc[2][reg] + bhD[2]));
        const float hv = fmaf(zg, hpv[reg] - ng, ng);
        hpv[reg] = hv;
        const __bf16 hb = (__bf16)hv;
        const __bf16 lb = (__bf16)(hv - (float)hb);
        const unsigned pw = (unsigned)__builtin_bit_cast(unsigned short, hb) |
                            ((unsigned)__builtin_bit_cast(unsigned short, lb) << 16);
        ast32(hn + (size_t)row * HID + cg, pw);
      }
    }
    gbar(cnt, 8u * (unsigned)(SEQL + 2 * t + 1));

    // ---- phase 2: fc1 = relu(h @ w1^T + b1) ----
    {
      stage_h16(sm, ((t + 1) & 1) ? hp1 : hp0, row0, tid);
      __syncthreads();
      f32x4 fa = zf;
      gh1(sm, rl, kbb, w1h, w1l, boff_fc, fa);
#pragma unroll
      for (int reg = 0; reg < 4; ++reg) {
        const int row = row0 + crow + reg;
        astf(&fc1[(size_t)row * HID + cg], fmaxf(fa[reg] + b1c, 0.0f));
      }
    }
    gbar(cnt, 8u * (unsigned)(SEQL + 2 * t + 2));
  }

  // ---- final y for t = H-1 ----
  if (ct == 0) {
#pragma unroll
    for (int rr = 0; rr < 4; ++rr) {
      const int row = row0 + (wv << 2) + rr;
      const unsigned long long* fp = (const unsigned long long*)fc1 + ((size_t)row << 8);
      float s = 0.0f;
#pragma unroll
      for (int j = 0; j < 4; ++j) {
        const unsigned long long w = ald64(fp + lane + (j << 6));
        const float f0 = __builtin_bit_cast(float, (unsigned)(w & 0xffffffffULL));
        const float f1 = __builtin_bit_cast(float, (unsigned)(w >> 32));
        s = fmaf(f0, w2p0[j], fmaf(f1, w2p1[j], s));
      }
#pragma unroll
      for (int off = 1; off < 64; off <<= 1) s += __shfl_xor(s, off, 64);
      if (lane == 0) yb[(wv << 2) + rr] = s + b2v;
    }
    __syncthreads();
    if (tid < 16) out[(size_t)(H - 1) * BATCH + row0 + tid] = yb[tid];
  }
}

extern "C" void kernel_launch(void* const* d_in, const int* in_sizes, int n_in,
                              void* d_out, int out_size, void* d_ws, size_t ws_size,
                              hipStream_t stream) {
  if (ws_size < WS_NEED) return;

  const float* src = (const float*)d_in[0];
  const float* enc_wih = (const float*)d_in[1];
  const float* enc_whh = (const float*)d_in[2];
  const float* enc_bih = (const float*)d_in[3];
  const float* enc_bhh = (const float*)d_in[4];
  const float* dec_wih = (const float*)d_in[5];
  const float* dec_whh = (const float*)d_in[6];
  const float* dec_bih = (const float*)d_in[7];
  const float* dec_bhh = (const float*)d_in[8];
  const float* w1 = (const float*)d_in[9];
  const float* b1 = (const float*)d_in[10];
  const float* w2 = (const float*)d_in[11];
  const float* b2 = (const float*)d_in[12];
  const int* hor = (const int*)d_in[13];
  float* out = (float*)d_out;
  char* ws = (char*)d_ws;

  hipMemsetAsync(ws + OFF_BAR, 0, 8192, stream);  // zero barrier counters every call

  split_w<<<dim3(3072), dim3(256), 0, stream>>>(enc_whh, (__bf16*)(ws + OFF_ENH),
                                                (__bf16*)(ws + OFF_ENL), 786432);
  split_w<<<dim3(3072), dim3(256), 0, stream>>>(dec_whh, (__bf16*)(ws + OFF_DEH),
                                                (__bf16*)(ws + OFF_DEL), 786432);
  split_w<<<dim3(1024), dim3(256), 0, stream>>>(w1, (__bf16*)(ws + OFF_W1H),
                                                (__bf16*)(ws + OFF_W1L), 262144);

  // Plain (non-cooperative) launch: grid == exact co-residency capacity.
  seq2seq_main<<<dim3(NWG), dim3(NTHR), 0, stream>>>(
      src, enc_wih, enc_bih, enc_bhh, dec_wih, dec_bih, dec_bhh, b1, w2, b2, hor, out, ws);
}